// Round 13
// baseline (2634.650 us; speedup 1.0000x reference)
//
#include <hip/hip_runtime.h>
#include <hip/hip_bf16.h>

#define N_NODES 50000
#define DIN     256
#define DOUT    128
#define NCLS    2
#define NHOP    2
#define NDEV    3
#define EDG     500000
#define TE      (NDEV*EDG)
#define NMASK   10000
#define LOSS_BLOCKS 2500             // one masked node per wave

#define BUCK    64
#define NBUCK   782                  // ceil(50000/64)
#define CH      2048                 // edges per binning block
#define NBLKA   733                  // ceil(TE/CH)
#define BHN     (NBUCK*NBLKA)        // 573,206
#define SCT     512
#define SCANBLKS ((BHN + SCT - 1) / SCT)   // 1120

typedef __attribute__((ext_vector_type(8))) short bf16x8;   // 8 bf16 = 4 VGPRs
typedef __attribute__((ext_vector_type(4))) float f32x4;
typedef __attribute__((ext_vector_type(2))) float f32x2;

__device__ __forceinline__ float softplusf(float a) {
    return fmaxf(a, 0.f) + log1pf(expf(-fabsf(a)));
}

// fp8 e4m3 (OCP on gfx950) helpers via HW pack/unpack
__device__ __forceinline__ f32x2 fp8lo(unsigned g) {
    return __builtin_amdgcn_cvt_pk_f32_fp8(g, false);
}
__device__ __forceinline__ f32x2 fp8hi(unsigned g) {
    return __builtin_amdgcn_cvt_pk_f32_fp8(g, true);
}
__device__ __forceinline__ unsigned char fp8enc1(float v) {
    return (unsigned char)(__builtin_amdgcn_cvt_pk_fp8_f32(v, v, 0, false) & 0xFF);
}

// ---------------- bucket-binned edge grouping (write-amp ~1x) ----------------

__global__ __launch_bounds__(256) void k_bhist(const int* __restrict__ dst,
                                               int* __restrict__ bh) {
    __shared__ int hist[NBUCK];
    int blk = blockIdx.x, tid = threadIdx.x;
    for (int i = tid; i < NBUCK; i += 256) hist[i] = 0;
    __syncthreads();
    int base = blk * CH;
    int lim = min(base + CH, TE);
    for (int i = base + tid; i < lim; i += 256) atomicAdd(&hist[dst[i] >> 6], 1);
    __syncthreads();
    for (int i = tid; i < NBUCK; i += 256) bh[(size_t)i * NBLKA + blk] = hist[i];
}

__global__ __launch_bounds__(SCT) void k_scanA(const int* __restrict__ in,
                                               int* __restrict__ out,
                                               int* __restrict__ bsums, int n) {
    __shared__ int s[SCT];
    int tid = threadIdx.x, gid = blockIdx.x * SCT + tid;
    int v = (gid < n) ? in[gid] : 0;
    s[tid] = v; __syncthreads();
    for (int o = 1; o < SCT; o <<= 1) {
        int t = (tid >= o) ? s[tid - o] : 0;
        __syncthreads();
        s[tid] += t;
        __syncthreads();
    }
    if (gid < n) out[gid] = s[tid] - v;          // exclusive
    if (tid == SCT - 1) bsums[blockIdx.x] = s[SCT - 1];
}

// single-block carry-looped exclusive scan (handles nb > SCT)
__global__ __launch_bounds__(SCT) void k_scanB(int* __restrict__ bsums, int nb) {
    __shared__ int s[SCT];
    int tid = threadIdx.x;
    int carry = 0;
    for (int base = 0; base < nb; base += SCT) {
        int v = (base + tid < nb) ? bsums[base + tid] : 0;
        s[tid] = v; __syncthreads();
        for (int o = 1; o < SCT; o <<= 1) {
            int t = (tid >= o) ? s[tid - o] : 0;
            __syncthreads();
            s[tid] += t;
            __syncthreads();
        }
        if (base + tid < nb) bsums[base + tid] = s[tid] - v + carry;
        carry += s[SCT - 1];
        __syncthreads();
    }
}

__global__ __launch_bounds__(SCT) void k_scanC(int* __restrict__ out,
                                               const int* __restrict__ bsums, int n) {
    int gid = blockIdx.x * SCT + threadIdx.x;
    if (gid < n) out[gid] += bsums[blockIdx.x];
}

// bin edges into bucket-grouped array; pack src(16) | dev(2)<<16 | dstlocal(6)<<18
__global__ __launch_bounds__(256) void k_bbin(const int* __restrict__ src,
                                              const int* __restrict__ dst,
                                              const float* __restrict__ vals,
                                              const int* __restrict__ sc,
                                              uint2* __restrict__ ebkt) {
    __shared__ int cur[NBUCK];
    int blk = blockIdx.x, tid = threadIdx.x;
    for (int i = tid; i < NBUCK; i += 256) cur[i] = sc[(size_t)i * NBLKA + blk];
    __syncthreads();
    int base = blk * CH;
    int lim = min(base + CH, TE);
    for (int i = base + tid; i < lim; i += 256) {
        int d = i / EDG;
        int n = dst[i];
        int bu = n >> 6;
        int pos = atomicAdd(&cur[bu], 1);
        ebkt[pos] = make_uint2((unsigned)src[i] | ((unsigned)d << 16) |
                               ((unsigned)(n & 63) << 18),
                               __float_as_uint(vals[i]));
    }
}

// merged conversions: h0->fp8 | x->bf16 | Ws/Vs transpose+bf16 (one launch)
#define PREP_A (N_NODES * DOUT / 4)          // float4 units of h0
#define PREP_B (N_NODES * DIN / 2)           // float2 units of x
#define PREP_W (NHOP * (DIN * DOUT + DOUT * DOUT))
__global__ __launch_bounds__(256) void k_prep(const float* __restrict__ h0,
                                              unsigned char* __restrict__ h8,
                                              const float* __restrict__ x,
                                              __hip_bfloat16* __restrict__ xb,
                                              const float* __restrict__ Ws,
                                              const float* __restrict__ Vs,
                                              __hip_bfloat16* __restrict__ WsT,
                                              __hip_bfloat16* __restrict__ VsT) {
    int i = blockIdx.x * 256 + threadIdx.x;
    if (i < PREP_A) {
        float4 f = ((const float4*)h0)[i];
        int r = 0;
        r = __builtin_amdgcn_cvt_pk_fp8_f32(f.x, f.y, r, false);
        r = __builtin_amdgcn_cvt_pk_fp8_f32(f.z, f.w, r, true);
        ((unsigned*)h8)[i] = (unsigned)r;
    } else if (i < PREP_A + PREP_B) {
        int j = i - PREP_A;
        float2 f = ((const float2*)x)[j];
        __hip_bfloat162 b;
        b.x = __float2bfloat16(f.x);
        b.y = __float2bfloat16(f.y);
        ((__hip_bfloat162*)xb)[j] = b;
    } else {
        int j = i - PREP_A - PREP_B;
        if (j < NHOP * DIN * DOUT) {
            int hop = j / (DIN * DOUT);
            int r = j % (DIN * DOUT);
            int k = r >> 7, n = r & 127;
            WsT[(size_t)hop * DOUT * DIN + (size_t)n * DIN + k] = __float2bfloat16(Ws[j]);
        } else if (j < PREP_W) {
            int j2 = j - NHOP * DIN * DOUT;
            int hop = j2 / (DOUT * DOUT);
            int r = j2 % (DOUT * DOUT);
            int k = r >> 7, n = r & 127;
            VsT[(size_t)hop * DOUT * DOUT + (size_t)n * DOUT + k] = __float2bfloat16(Vs[j2]);
        }
    }
}

// ---------------- bucket-local LDS scatter-add aggregation ----------------
// One block per 64-node bucket. Each 32-lane half-wave owns one edge/iter:
// lane c gathers dword c of the fp8 row, multiplies by w = val*alpha[dev],
// atomically adds 4 floats into agg[dstlocal]. No per-node reduction, no sort.
__global__ __launch_bounds__(256) void k_agg2(const unsigned char* __restrict__ h8,
                                              const uint2* __restrict__ ebkt,
                                              const int* __restrict__ sc,
                                              const float* __restrict__ alpha_hop,
                                              __hip_bfloat16* __restrict__ aggcb) {
    __shared__ float agg[BUCK][DOUT + 4];   // stride 132 floats: spreads dl across banks
    int b = blockIdx.x, tid = threadIdx.x;
    float a0 = alpha_hop[0], a1 = alpha_hop[1], a2 = alpha_hop[2];
    for (int i = tid; i < BUCK * (DOUT + 4); i += 256) ((float*)agg)[i] = 0.f;
    __syncthreads();
    int beg = sc[(size_t)b * NBLKA];
    int end = (b + 1 < NBUCK) ? sc[(size_t)(b + 1) * NBLKA] : TE;
    int hw = tid >> 5;        // half-wave id 0..7: one edge each per iter
    int c  = tid & 31;        // dword of the 128B fp8 row
    for (int e = beg + hw; e < end; e += 8) {
        uint2 q = ebkt[e];                               // 32-lane broadcast
        int dl = (q.x >> 18) & 63;
        int d  = (q.x >> 16) & 3;
        float w = __uint_as_float(q.y) * (d == 0 ? a0 : (d == 1 ? a1 : a2));
        unsigned g = *(const unsigned*)(h8 + (size_t)(q.x & 0xFFFFu) * DOUT + c * 4);
        f32x2 lo = fp8lo(g), hi = fp8hi(g);
        atomicAdd(&agg[dl][c * 4 + 0], w * lo[0]);
        atomicAdd(&agg[dl][c * 4 + 1], w * lo[1]);
        atomicAdd(&agg[dl][c * 4 + 2], w * hi[0]);
        atomicAdd(&agg[dl][c * 4 + 3], w * hi[1]);
    }
    __syncthreads();
    // write out 64 x 128 bf16, coalesced (8 cols per thread-iter)
    int node0 = b * BUCK;
    for (int i = tid; i < BUCK * (DOUT / 8); i += 256) {
        int r = i >> 4, c8 = (i & 15) * 8;
        int node = node0 + r;
        if (node < N_NODES) {
            union { __hip_bfloat16 h[8]; uint4 u; } pk;
#pragma unroll
            for (int j = 0; j < 8; ++j) pk.h[j] = __float2bfloat16(agg[r][c8 + j]);
            *(uint4*)(aggcb + (size_t)node * DOUT + c8) = pk.u;
        }
    }
}

// ---------------- fused MFMA GEMM: h = sigmoid(A1@B1 + A2@B2), bf16 in --------------
// BM=64 tile (782 blocks -> ~3 blocks/CU, balanced), 4 waves (2x2), wave = 32x64 via
// 2x4 mfma_f32_16x16x32_bf16 frags. LDS-staged A and B (verified-better vs direct).
__global__ __launch_bounds__(256) void k_mm(const __hip_bfloat16* __restrict__ A1,
                                            const __hip_bfloat16* __restrict__ BT1,
                                            const __hip_bfloat16* __restrict__ A2,
                                            const __hip_bfloat16* __restrict__ BT2,
                                            unsigned char* __restrict__ C8,
                                            __hip_bfloat16* __restrict__ Cbf,
                                            int M, int K1, int K2) {
    __shared__ short As[64][40];    // stride 40: bank-starts spread, <=2-way (free)
    __shared__ short Bs[128][40];
    int tid = threadIdx.x;
    int lane = tid & 63;
    int w = tid >> 6;
    int wr = (w >> 1) * 32, wc = (w & 1) * 64;
    int lr = lane & 15, kg = lane >> 4;
    int row0 = blockIdx.x * 64;

    f32x4 acc[2][4];
#pragma unroll
    for (int mi = 0; mi < 2; ++mi)
#pragma unroll
        for (int ni = 0; ni < 4; ++ni) acc[mi][ni] = (f32x4){0.f, 0.f, 0.f, 0.f};

#pragma unroll
    for (int seg = 0; seg < 2; ++seg) {
        const __hip_bfloat16* A = seg ? A2 : A1;
        const __hip_bfloat16* BT = seg ? BT2 : BT1;
        int K = seg ? K2 : K1;
        for (int k0 = 0; k0 < K; k0 += 32) {
            {   // stage A tile: 256 x 16B chunks, 1 per thread
                int r = tid >> 2, kc = (tid & 3) * 8;
                bf16x8 g = {};
                int gr = row0 + r;
                if (gr < M) g = *(const bf16x8*)(A + (size_t)gr * K + k0 + kc);
                *(bf16x8*)&As[r][kc] = g;
            }
#pragma unroll
            for (int j = 0; j < 2; ++j) {           // stage BT tile: 512 chunks
                int c = tid + j * 256;
                int r = c >> 2, kc = (c & 3) * 8;
                *(bf16x8*)&Bs[r][kc] = *(const bf16x8*)(BT + (size_t)r * K + k0 + kc);
            }
            __syncthreads();
            bf16x8 af[2], bfr[4];
#pragma unroll
            for (int i = 0; i < 2; ++i)
                af[i] = *(const bf16x8*)&As[wr + i * 16 + lr][kg * 8];
#pragma unroll
            for (int i = 0; i < 4; ++i)
                bfr[i] = *(const bf16x8*)&Bs[wc + i * 16 + lr][kg * 8];
#pragma unroll
            for (int mi = 0; mi < 2; ++mi)
#pragma unroll
                for (int ni = 0; ni < 4; ++ni)
                    acc[mi][ni] = __builtin_amdgcn_mfma_f32_16x16x32_bf16(
                        af[mi], bfr[ni], acc[mi][ni], 0, 0, 0);
            __syncthreads();
        }
    }

#pragma unroll
    for (int mi = 0; mi < 2; ++mi) {
#pragma unroll
        for (int r = 0; r < 4; ++r) {
            int row = row0 + wr + mi * 16 + kg * 4 + r;   // C/D: row=(lane>>4)*4+reg
            if (row < M) {
#pragma unroll
                for (int ni = 0; ni < 4; ++ni) {
                    int col = wc + ni * 16 + lr;          // C/D: col=lane&15
                    float v = acc[mi][ni][r];
                    v = 1.f / (1.f + __expf(-v));
                    if (C8)  C8[(size_t)row * DOUT + col] = fp8enc1(v);
                    if (Cbf) Cbf[(size_t)row * DOUT + col] = __float2bfloat16(v);
                }
            }
        }
    }
}

// ---------------- masked loss + accuracy: one node per wave ----------------
__global__ __launch_bounds__(256) void k_loss(const __hip_bfloat16* __restrict__ h,
                                              const float* __restrict__ label,
                                              const int* __restrict__ idx,
                                              const float* __restrict__ u,
                                              const float* __restrict__ Wc,
                                              const float* __restrict__ bb,
                                              float* __restrict__ blockpart, int Mtot) {
    __shared__ float sl[4], sc2[4];
    int wid = threadIdx.x >> 6;
    int lane = threadIdx.x & 63;
    int w = blockIdx.x * 4 + wid;
    float lsum = 0.f, csum = 0.f;
    if (w < Mtot) {
        int node = idx[w];
        float v0 = __bfloat162float(h[(size_t)node * DOUT + lane]);
        float v1 = __bfloat162float(h[(size_t)node * DOUT + 64 + lane]);
        float ps = v0 * u[lane] + v1 * u[64 + lane];
        float p0 = v0 * Wc[lane * 2 + 0] + v1 * Wc[(lane + 64) * 2 + 0];
        float p1 = v0 * Wc[lane * 2 + 1] + v1 * Wc[(lane + 64) * 2 + 1];
#pragma unroll
        for (int o = 32; o > 0; o >>= 1) {
            ps += __shfl_xor(ps, o, 64);
            p0 += __shfl_xor(p0, o, 64);
            p1 += __shfl_xor(p1, o, 64);
        }
        if (lane == 0) {
            float y0 = label[(size_t)node * NCLS + 0];
            float y1 = label[(size_t)node * NCLS + 1];
            lsum = softplusf(-(y0 * ps)) + softplusf(-(y1 * ps));
            float l0 = p0 + bb[0], l1 = p1 + bb[1];
            int pred = (l1 > l0) ? 1 : 0;
            int truth = (y1 > y0) ? 1 : 0;
            csum = (pred == truth) ? 1.f : 0.f;
        }
    }
    if (lane == 0) { sl[wid] = lsum; sc2[wid] = csum; }
    __syncthreads();
    if (threadIdx.x == 0) {
        blockpart[blockIdx.x * 2 + 0] = sl[0] + sl[1] + sl[2] + sl[3];
        blockpart[blockIdx.x * 2 + 1] = sc2[0] + sc2[1] + sc2[2] + sc2[3];
    }
}

__global__ __launch_bounds__(256) void k_final(const float* __restrict__ bp,
                                               float* __restrict__ out, int nb) {
    __shared__ float sl[256], sc2[256];
    int t = threadIdx.x;
    float l = 0.f, c = 0.f;
    for (int i = t; i < nb; i += 256) { l += bp[i * 2]; c += bp[i * 2 + 1]; }
    sl[t] = l; sc2[t] = c;
    __syncthreads();
    for (int o = 128; o > 0; o >>= 1) {
        if (t < o) { sl[t] += sl[t + o]; sc2[t] += sc2[t + o]; }
        __syncthreads();
    }
    if (t == 0) { out[0] = sl[0]; out[1] = sc2[0] * (1.0f / NMASK); }
}

// ---------------- launch ----------------
extern "C" void kernel_launch(void* const* d_in, const int* in_sizes, int n_in,
                              void* d_out, int out_size, void* d_ws, size_t ws_size,
                              hipStream_t stream) {
    const float* x      = (const float*)d_in[0];
    const float* label  = (const float*)d_in[1];
    const int*   idx    = (const int*)d_in[2];
    const int*   src    = (const int*)d_in[3];
    const int*   dst    = (const int*)d_in[4];
    const float* vals   = (const float*)d_in[5];
    const float* h0     = (const float*)d_in[6];
    const float* Ws     = (const float*)d_in[7];
    const float* Vs     = (const float*)d_in[8];
    const float* alphas = (const float*)d_in[9];
    const float* Wc     = (const float*)d_in[10];
    const float* bb     = (const float*)d_in[11];
    const float* u      = (const float*)d_in[12];
    float* out = (float*)d_out;

    char* p = (char*)d_ws;
    __hip_bfloat16* aggcb = (__hip_bfloat16*)p; p += (size_t)N_NODES * DOUT * 2;  // 12.8 MB
    __hip_bfloat16* xb    = (__hip_bfloat16*)p; p += (size_t)N_NODES * DIN * 2;   // 25.6 MB
    unsigned char*  h8    = (unsigned char*)p;  p += (size_t)N_NODES * DOUT;      // 6.4 MB
    __hip_bfloat16* hbf   = (__hip_bfloat16*)p; p += (size_t)N_NODES * DOUT * 2;  // 12.8 MB
    uint2*          ebkt  = (uint2*)p;          p += (size_t)TE * 8;              // 12 MB (lives both hops)
    int*            bh    = (int*)p;            p += (size_t)BHN * 4;             // 2.3 MB
    int*            sc    = (int*)p;            p += (size_t)BHN * 4;             // 2.3 MB
    int*            bsums = (int*)p;            p += 4096 * 4;
    __hip_bfloat16* WsT   = (__hip_bfloat16*)p; p += (size_t)NHOP * DOUT * DIN * 2;  // 128 KB
    __hip_bfloat16* VsT   = (__hip_bfloat16*)p; p += (size_t)NHOP * DOUT * DOUT * 2; // 64 KB
    float*          blockpart = (float*)p;      p += LOSS_BLOCKS * 2 * 4;         // 20 KB

    // bucket-grouped edge build (one array, reused by both hops)
    k_bhist<<<NBLKA, 256, 0, stream>>>(dst, bh);
    k_scanA<<<SCANBLKS, SCT, 0, stream>>>(bh, sc, bsums, BHN);
    k_scanB<<<1, SCT, 0, stream>>>(bsums, SCANBLKS);
    k_scanC<<<SCANBLKS, SCT, 0, stream>>>(sc, bsums, BHN);
    k_bbin<<<NBLKA, 256, 0, stream>>>(src, dst, vals, sc, ebkt);

    // merged conversions: h0->fp8, x->bf16, weights transposed (one launch)
    const int PREPBLK = (PREP_A + PREP_B + PREP_W + 255) / 256;
    k_prep<<<PREPBLK, 256, 0, stream>>>(h0, h8, x, xb, Ws, Vs, WsT, VsT);

    const int MMBLK = (N_NODES + 63) / 64;  // 782
    // hop 1: bucket scatter-add agg of h0(fp8); h1 = sigmoid(x@W0 + agg@V0) -> fp8
    k_agg2<<<NBUCK, 256, 0, stream>>>(h8, ebkt, sc, alphas, aggcb);
    k_mm<<<MMBLK, 256, 0, stream>>>(xb, WsT, aggcb, VsT, h8, nullptr, N_NODES, DIN, DOUT);
    // hop 2: agg of h1(fp8); h2 = sigmoid(x@W1 + agg@V1) -> bf16 (for loss)
    k_agg2<<<NBUCK, 256, 0, stream>>>(h8, ebkt, sc, alphas + NDEV, aggcb);
    k_mm<<<MMBLK, 256, 0, stream>>>(xb, WsT + (size_t)DOUT * DIN, aggcb,
                                    VsT + (size_t)DOUT * DOUT, nullptr, hbf,
                                    N_NODES, DIN, DOUT);

    k_loss<<<LOSS_BLOCKS, 256, 0, stream>>>(hbf, label, idx, u, Wc, bb, blockpart, NMASK);
    k_final<<<1, 256, 0, stream>>>(blockpart, out, LOSS_BLOCKS);
}

// Round 14
// 189.879 us; speedup vs baseline: 13.8754x; 13.8754x over previous
//
#include <hip/hip_runtime.h>
#include <hip/hip_bf16.h>

#define N_NODES 50000
#define DIN     256
#define DOUT    128
#define NCLS    2
#define NHOP    2
#define NDEV    3
#define EDG     500000
#define TE      (NDEV*EDG)
#define NMASK   10000
#define LOSS_BLOCKS 2500             // one masked node per wave

#define BUCK    128
#define NBUCK   391                  // ceil(50000/128)
#define CH      2048                 // edges per binning block
#define NBLKA   733                  // ceil(TE/CH)
#define BHN     (NBUCK*NBLKA)        // 286,603
#define SCT     512
#define SCANBLKS ((BHN + SCT - 1) / SCT)   // 560

typedef __attribute__((ext_vector_type(8))) short bf16x8;   // 8 bf16 = 4 VGPRs
typedef __attribute__((ext_vector_type(4))) float f32x4;
typedef __attribute__((ext_vector_type(2))) float f32x2;

__device__ __forceinline__ float softplusf(float a) {
    return fmaxf(a, 0.f) + log1pf(expf(-fabsf(a)));
}

// fp8 e4m3 (OCP on gfx950) helpers via HW pack/unpack
__device__ __forceinline__ f32x2 fp8lo(unsigned g) {
    return __builtin_amdgcn_cvt_pk_f32_fp8(g, false);
}
__device__ __forceinline__ f32x2 fp8hi(unsigned g) {
    return __builtin_amdgcn_cvt_pk_f32_fp8(g, true);
}
__device__ __forceinline__ unsigned char fp8enc1(float v) {
    return (unsigned char)(__builtin_amdgcn_cvt_pk_fp8_f32(v, v, 0, false) & 0xFF);
}

// ---------------- bucket-binned CSR build (write-amp ~1x) ----------------

__global__ __launch_bounds__(256) void k_bhist(const int* __restrict__ dst,
                                               int* __restrict__ bh) {
    __shared__ int hist[NBUCK];
    int blk = blockIdx.x, tid = threadIdx.x;
    for (int i = tid; i < NBUCK; i += 256) hist[i] = 0;
    __syncthreads();
    int base = blk * CH;
    int lim = min(base + CH, TE);
    for (int i = base + tid; i < lim; i += 256) atomicAdd(&hist[dst[i] >> 7], 1);
    __syncthreads();
    for (int i = tid; i < NBUCK; i += 256) bh[(size_t)i * NBLKA + blk] = hist[i];
}

__global__ __launch_bounds__(SCT) void k_scanA(const int* __restrict__ in,
                                               int* __restrict__ out,
                                               int* __restrict__ bsums, int n) {
    __shared__ int s[SCT];
    int tid = threadIdx.x, gid = blockIdx.x * SCT + tid;
    int v = (gid < n) ? in[gid] : 0;
    s[tid] = v; __syncthreads();
    for (int o = 1; o < SCT; o <<= 1) {
        int t = (tid >= o) ? s[tid - o] : 0;
        __syncthreads();
        s[tid] += t;
        __syncthreads();
    }
    if (gid < n) out[gid] = s[tid] - v;          // exclusive
    if (tid == SCT - 1) bsums[blockIdx.x] = s[SCT - 1];
}

// single-block carry-looped exclusive scan (handles nb > SCT)
__global__ __launch_bounds__(SCT) void k_scanB(int* __restrict__ bsums, int nb) {
    __shared__ int s[SCT];
    int tid = threadIdx.x;
    int carry = 0;
    for (int base = 0; base < nb; base += SCT) {
        int v = (base + tid < nb) ? bsums[base + tid] : 0;
        s[tid] = v; __syncthreads();
        for (int o = 1; o < SCT; o <<= 1) {
            int t = (tid >= o) ? s[tid - o] : 0;
            __syncthreads();
            s[tid] += t;
            __syncthreads();
        }
        if (base + tid < nb) bsums[base + tid] = s[tid] - v + carry;
        carry += s[SCT - 1];
        __syncthreads();
    }
}

__global__ __launch_bounds__(SCT) void k_scanC(int* __restrict__ out,
                                               const int* __restrict__ bsums, int n) {
    int gid = blockIdx.x * SCT + threadIdx.x;
    if (gid < n) out[gid] += bsums[blockIdx.x];
}

// bin edges into bucket-grouped array; pack src(16) | dev(2)<<16 | dstlocal(7)<<18
__global__ __launch_bounds__(256) void k_bbin(const int* __restrict__ src,
                                              const int* __restrict__ dst,
                                              const float* __restrict__ vals,
                                              const int* __restrict__ sc,
                                              uint2* __restrict__ ebkt) {
    __shared__ int cur[NBUCK];
    int blk = blockIdx.x, tid = threadIdx.x;
    for (int i = tid; i < NBUCK; i += 256) cur[i] = sc[(size_t)i * NBLKA + blk];
    __syncthreads();
    int base = blk * CH;
    int lim = min(base + CH, TE);
    for (int i = base + tid; i < lim; i += 256) {
        int d = i / EDG;
        int n = dst[i];
        int bu = n >> 7;
        int pos = atomicAdd(&cur[bu], 1);
        ebkt[pos] = make_uint2((unsigned)src[i] | ((unsigned)d << 16) |
                               ((unsigned)(n & 127) << 18),
                               __float_as_uint(vals[i]));
    }
}

// per-bucket counting sort by node; emits {src|dev<<16, val} edge array + offsets
__global__ __launch_bounds__(256) void k_bsort(const uint2* __restrict__ ebkt,
                                               const int* __restrict__ sc,
                                               uint2* __restrict__ edh,
                                               int* __restrict__ offs) {
    __shared__ int cnt[BUCK], start[BUCK + 1], cur[BUCK];
    int b = blockIdx.x, tid = threadIdx.x;
    int beg = sc[(size_t)b * NBLKA];
    int end = (b + 1 < NBUCK) ? sc[(size_t)(b + 1) * NBLKA] : TE;
    if (tid < BUCK) { cnt[tid] = 0; cur[tid] = 0; }
    __syncthreads();
    for (int e = beg + tid; e < end; e += 256)
        atomicAdd(&cnt[(ebkt[e].x >> 18) & 127], 1);
    __syncthreads();
    if (tid == 0) {
        int acc = 0;
        for (int i = 0; i < BUCK; ++i) { start[i] = acc; acc += cnt[i]; }
        start[BUCK] = acc;
    }
    __syncthreads();
    if (tid < BUCK) {
        int n = b * BUCK + tid;
        if (n < N_NODES) offs[n] = beg + start[tid];
    }
    if (b == 0 && tid == 255) offs[N_NODES] = TE;
    for (int e = beg + tid; e < end; e += 256) {
        uint2 v = ebkt[e];
        int dl = (v.x >> 18) & 127;
        int pos = beg + start[dl] + atomicAdd(&cur[dl], 1);
        edh[pos] = make_uint2(v.x & 0x3FFFFu, v.y);   // src | dev<<16, val
    }
}

// merged conversions: h0->fp8 | x->bf16 | Ws/Vs transpose+bf16 (one launch)
#define PREP_A (N_NODES * DOUT / 4)          // float4 units of h0
#define PREP_B (N_NODES * DIN / 2)           // float2 units of x
#define PREP_W (NHOP * (DIN * DOUT + DOUT * DOUT))
__global__ __launch_bounds__(256) void k_prep(const float* __restrict__ h0,
                                              unsigned char* __restrict__ h8,
                                              const float* __restrict__ x,
                                              __hip_bfloat16* __restrict__ xb,
                                              const float* __restrict__ Ws,
                                              const float* __restrict__ Vs,
                                              __hip_bfloat16* __restrict__ WsT,
                                              __hip_bfloat16* __restrict__ VsT) {
    int i = blockIdx.x * 256 + threadIdx.x;
    if (i < PREP_A) {
        float4 f = ((const float4*)h0)[i];
        int r = 0;
        r = __builtin_amdgcn_cvt_pk_fp8_f32(f.x, f.y, r, false);
        r = __builtin_amdgcn_cvt_pk_fp8_f32(f.z, f.w, r, true);
        ((unsigned*)h8)[i] = (unsigned)r;
    } else if (i < PREP_A + PREP_B) {
        int j = i - PREP_A;
        float2 f = ((const float2*)x)[j];
        __hip_bfloat162 b;
        b.x = __float2bfloat16(f.x);
        b.y = __float2bfloat16(f.y);
        ((__hip_bfloat162*)xb)[j] = b;
    } else {
        int j = i - PREP_A - PREP_B;
        if (j < NHOP * DIN * DOUT) {
            int hop = j / (DIN * DOUT);
            int r = j % (DIN * DOUT);
            int k = r >> 7, n = r & 127;
            WsT[(size_t)hop * DOUT * DIN + (size_t)n * DIN + k] = __float2bfloat16(Ws[j]);
        } else if (j < PREP_W) {
            int j2 = j - NHOP * DIN * DOUT;
            int hop = j2 / (DOUT * DOUT);
            int r = j2 % (DOUT * DOUT);
            int k = r >> 7, n = r & 127;
            VsT[(size_t)hop * DOUT * DOUT + (size_t)n * DOUT + k] = __float2bfloat16(Vs[j2]);
        }
    }
}

// ---------------- sparse aggregation: one wave per node, 8 edges/iter --------------
// lane = grp(0..7)*8 + cw(0..7): group grp owns edge slot grp; lane loads 16B (16 fp8)
// of that edge's row at byte offset cw*16. 3-level shfl reduction folds the 8 groups.
// alpha applied at decode (meta is an 8-lane broadcast; 3 VALU per 8-edge batch).
__global__ __launch_bounds__(256) void k_agg(const unsigned char* __restrict__ h8,
                                             const uint2* __restrict__ edh,
                                             const int* __restrict__ offs,
                                             const float* __restrict__ alpha_hop,
                                             __hip_bfloat16* __restrict__ aggcb) {
    int wid = threadIdx.x >> 6;
    int lane = threadIdx.x & 63;
    int n = blockIdx.x * 4 + wid;
    if (n >= N_NODES) return;
    float a0 = alpha_hop[0], a1 = alpha_hop[1], a2 = alpha_hop[2];
    int grp = lane >> 3;         // edge slot within the 8-edge batch
    int cw = lane & 7;           // 16-byte chunk of the 128B fp8 row
    int beg = offs[n], end = offs[n + 1];
    float a[16];
#pragma unroll
    for (int j = 0; j < 16; ++j) a[j] = 0.f;

    for (int e = beg; e < end; e += 8) {
        int rem = end - e;
        int ee = e + (grp < rem ? grp : 0);
        uint2 q = edh[ee];                                   // {src|dev<<16, val}
        int d = (q.x >> 16) & 3;
        float wt = __uint_as_float(q.y) * (d == 0 ? a0 : (d == 1 ? a1 : a2));
        wt = (grp < rem) ? wt : 0.f;
        uint4 g = *(const uint4*)(h8 + (size_t)(q.x & 0xFFFFu) * DOUT + cw * 16);
#pragma unroll
        for (int wv = 0; wv < 4; ++wv) {
            unsigned gw = (&g.x)[wv];
            f32x2 lo = fp8lo(gw), hi = fp8hi(gw);
            a[wv * 4 + 0] += wt * lo[0];
            a[wv * 4 + 1] += wt * lo[1];
            a[wv * 4 + 2] += wt * hi[0];
            a[wv * 4 + 3] += wt * hi[1];
        }
    }
    // fold the 8 edge-groups (lane bits 3,4,5)
#pragma unroll
    for (int j = 0; j < 16; ++j) {
        a[j] += __shfl_xor(a[j], 8, 64);
        a[j] += __shfl_xor(a[j], 16, 64);
        a[j] += __shfl_xor(a[j], 32, 64);
    }
    if (grp == 0) {               // lanes 0..7 write cols cw*16 .. cw*16+15
        union { __hip_bfloat16 h[8]; uint4 u; } pk0, pk1;
#pragma unroll
        for (int j = 0; j < 8; ++j) {
            pk0.h[j] = __float2bfloat16(a[j]);
            pk1.h[j] = __float2bfloat16(a[8 + j]);
        }
        *(uint4*)(aggcb + (size_t)n * DOUT + cw * 16) = pk0.u;
        *(uint4*)(aggcb + (size_t)n * DOUT + cw * 16 + 8) = pk1.u;
    }
}

// ---------------- fused MFMA GEMM: h = sigmoid(A1@B1 + A2@B2), bf16 in --------------
// BM=64 tile (782 blocks -> ~3 blocks/CU, balanced), 4 waves (2x2), wave = 32x64 via
// 2x4 mfma_f32_16x16x32_bf16 frags. LDS-staged A and B (verified-better vs direct).
__global__ __launch_bounds__(256) void k_mm(const __hip_bfloat16* __restrict__ A1,
                                            const __hip_bfloat16* __restrict__ BT1,
                                            const __hip_bfloat16* __restrict__ A2,
                                            const __hip_bfloat16* __restrict__ BT2,
                                            unsigned char* __restrict__ C8,
                                            __hip_bfloat16* __restrict__ Cbf,
                                            int M, int K1, int K2) {
    __shared__ short As[64][40];    // stride 40: bank-starts spread, <=2-way (free)
    __shared__ short Bs[128][40];
    int tid = threadIdx.x;
    int lane = tid & 63;
    int w = tid >> 6;
    int wr = (w >> 1) * 32, wc = (w & 1) * 64;
    int lr = lane & 15, kg = lane >> 4;
    int row0 = blockIdx.x * 64;

    f32x4 acc[2][4];
#pragma unroll
    for (int mi = 0; mi < 2; ++mi)
#pragma unroll
        for (int ni = 0; ni < 4; ++ni) acc[mi][ni] = (f32x4){0.f, 0.f, 0.f, 0.f};

#pragma unroll
    for (int seg = 0; seg < 2; ++seg) {
        const __hip_bfloat16* A = seg ? A2 : A1;
        const __hip_bfloat16* BT = seg ? BT2 : BT1;
        int K = seg ? K2 : K1;
        for (int k0 = 0; k0 < K; k0 += 32) {
            {   // stage A tile: 256 x 16B chunks, 1 per thread
                int r = tid >> 2, kc = (tid & 3) * 8;
                bf16x8 g = {};
                int gr = row0 + r;
                if (gr < M) g = *(const bf16x8*)(A + (size_t)gr * K + k0 + kc);
                *(bf16x8*)&As[r][kc] = g;
            }
#pragma unroll
            for (int j = 0; j < 2; ++j) {           // stage BT tile: 512 chunks
                int c = tid + j * 256;
                int r = c >> 2, kc = (c & 3) * 8;
                *(bf16x8*)&Bs[r][kc] = *(const bf16x8*)(BT + (size_t)r * K + k0 + kc);
            }
            __syncthreads();
            bf16x8 af[2], bfr[4];
#pragma unroll
            for (int i = 0; i < 2; ++i)
                af[i] = *(const bf16x8*)&As[wr + i * 16 + lr][kg * 8];
#pragma unroll
            for (int i = 0; i < 4; ++i)
                bfr[i] = *(const bf16x8*)&Bs[wc + i * 16 + lr][kg * 8];
#pragma unroll
            for (int mi = 0; mi < 2; ++mi)
#pragma unroll
                for (int ni = 0; ni < 4; ++ni)
                    acc[mi][ni] = __builtin_amdgcn_mfma_f32_16x16x32_bf16(
                        af[mi], bfr[ni], acc[mi][ni], 0, 0, 0);
            __syncthreads();
        }
    }

#pragma unroll
    for (int mi = 0; mi < 2; ++mi) {
#pragma unroll
        for (int r = 0; r < 4; ++r) {
            int row = row0 + wr + mi * 16 + kg * 4 + r;   // C/D: row=(lane>>4)*4+reg
            if (row < M) {
#pragma unroll
                for (int ni = 0; ni < 4; ++ni) {
                    int col = wc + ni * 16 + lr;          // C/D: col=lane&15
                    float v = acc[mi][ni][r];
                    v = 1.f / (1.f + __expf(-v));
                    if (C8)  C8[(size_t)row * DOUT + col] = fp8enc1(v);
                    if (Cbf) Cbf[(size_t)row * DOUT + col] = __float2bfloat16(v);
                }
            }
        }
    }
}

// ---------------- masked loss + accuracy: one node per wave ----------------
__global__ __launch_bounds__(256) void k_loss(const __hip_bfloat16* __restrict__ h,
                                              const float* __restrict__ label,
                                              const int* __restrict__ idx,
                                              const float* __restrict__ u,
                                              const float* __restrict__ Wc,
                                              const float* __restrict__ bb,
                                              float* __restrict__ blockpart, int Mtot) {
    __shared__ float sl[4], sc2[4];
    int wid = threadIdx.x >> 6;
    int lane = threadIdx.x & 63;
    int w = blockIdx.x * 4 + wid;
    float lsum = 0.f, csum = 0.f;
    if (w < Mtot) {
        int node = idx[w];
        float v0 = __bfloat162float(h[(size_t)node * DOUT + lane]);
        float v1 = __bfloat162float(h[(size_t)node * DOUT + 64 + lane]);
        float ps = v0 * u[lane] + v1 * u[64 + lane];
        float p0 = v0 * Wc[lane * 2 + 0] + v1 * Wc[(lane + 64) * 2 + 0];
        float p1 = v0 * Wc[lane * 2 + 1] + v1 * Wc[(lane + 64) * 2 + 1];
#pragma unroll
        for (int o = 32; o > 0; o >>= 1) {
            ps += __shfl_xor(ps, o, 64);
            p0 += __shfl_xor(p0, o, 64);
            p1 += __shfl_xor(p1, o, 64);
        }
        if (lane == 0) {
            float y0 = label[(size_t)node * NCLS + 0];
            float y1 = label[(size_t)node * NCLS + 1];
            lsum = softplusf(-(y0 * ps)) + softplusf(-(y1 * ps));
            float l0 = p0 + bb[0], l1 = p1 + bb[1];
            int pred = (l1 > l0) ? 1 : 0;
            int truth = (y1 > y0) ? 1 : 0;
            csum = (pred == truth) ? 1.f : 0.f;
        }
    }
    if (lane == 0) { sl[wid] = lsum; sc2[wid] = csum; }
    __syncthreads();
    if (threadIdx.x == 0) {
        blockpart[blockIdx.x * 2 + 0] = sl[0] + sl[1] + sl[2] + sl[3];
        blockpart[blockIdx.x * 2 + 1] = sc2[0] + sc2[1] + sc2[2] + sc2[3];
    }
}

__global__ __launch_bounds__(256) void k_final(const float* __restrict__ bp,
                                               float* __restrict__ out, int nb) {
    __shared__ float sl[256], sc2[256];
    int t = threadIdx.x;
    float l = 0.f, c = 0.f;
    for (int i = t; i < nb; i += 256) { l += bp[i * 2]; c += bp[i * 2 + 1]; }
    sl[t] = l; sc2[t] = c;
    __syncthreads();
    for (int o = 128; o > 0; o >>= 1) {
        if (t < o) { sl[t] += sl[t + o]; sc2[t] += sc2[t + o]; }
        __syncthreads();
    }
    if (t == 0) { out[0] = sl[0]; out[1] = sc2[0] * (1.0f / NMASK); }
}

// ---------------- launch ----------------
extern "C" void kernel_launch(void* const* d_in, const int* in_sizes, int n_in,
                              void* d_out, int out_size, void* d_ws, size_t ws_size,
                              hipStream_t stream) {
    const float* x      = (const float*)d_in[0];
    const float* label  = (const float*)d_in[1];
    const int*   idx    = (const int*)d_in[2];
    const int*   src    = (const int*)d_in[3];
    const int*   dst    = (const int*)d_in[4];
    const float* vals   = (const float*)d_in[5];
    const float* h0     = (const float*)d_in[6];
    const float* Ws     = (const float*)d_in[7];
    const float* Vs     = (const float*)d_in[8];
    const float* alphas = (const float*)d_in[9];
    const float* Wc     = (const float*)d_in[10];
    const float* bb     = (const float*)d_in[11];
    const float* u      = (const float*)d_in[12];
    float* out = (float*)d_out;

    char* p = (char*)d_ws;
    __hip_bfloat16* aggcb = (__hip_bfloat16*)p; p += (size_t)N_NODES * DOUT * 2;  // 12.8 MB
    __hip_bfloat16* xb    = (__hip_bfloat16*)p; p += (size_t)N_NODES * DIN * 2;   // 25.6 MB
    unsigned char*  h8    = (unsigned char*)p;  p += (size_t)N_NODES * DOUT;      // 6.4 MB
    __hip_bfloat16* hbf   = (__hip_bfloat16*)p; p += (size_t)N_NODES * DOUT * 2;  // 12.8 MB
    uint2*          edh   = (uint2*)p;          p += (size_t)TE * 8;              // 12 MB
    int*            offs  = (int*)p;            p += 200064 * 4;                  // ~0.8 MB
    __hip_bfloat16* WsT   = (__hip_bfloat16*)p; p += (size_t)NHOP * DOUT * DIN * 2;  // 128 KB
    __hip_bfloat16* VsT   = (__hip_bfloat16*)p; p += (size_t)NHOP * DOUT * DOUT * 2; // 64 KB
    float*          blockpart = (float*)p;      p += LOSS_BLOCKS * 2 * 4;         // 20 KB
    // CSR-build scratch aliases xb (xb written by k_prep AFTER k_bsort; stream-serial)
    uint2* ebkt  = (uint2*)xb;                            // 12 MB
    int*   bh    = (int*)((char*)xb + (size_t)TE * 8);    // 1.15 MB
    int*   sc    = bh + BHN;                              // 1.15 MB
    int*   bsums = sc + BHN;

    // bucket-binned CSR build (single edge array, alpha applied in k_agg)
    k_bhist<<<NBLKA, 256, 0, stream>>>(dst, bh);
    k_scanA<<<SCANBLKS, SCT, 0, stream>>>(bh, sc, bsums, BHN);
    k_scanB<<<1, SCT, 0, stream>>>(bsums, SCANBLKS);
    k_scanC<<<SCANBLKS, SCT, 0, stream>>>(sc, bsums, BHN);
    k_bbin<<<NBLKA, 256, 0, stream>>>(src, dst, vals, sc, ebkt);
    k_bsort<<<NBUCK, 256, 0, stream>>>(ebkt, sc, edh, offs);

    // merged conversions: h0->fp8, x->bf16, weights transposed (one launch)
    const int PREPBLK = (PREP_A + PREP_B + PREP_W + 255) / 256;
    k_prep<<<PREPBLK, 256, 0, stream>>>(h0, h8, x, xb, Ws, Vs, WsT, VsT);

    const int MMBLK = (N_NODES + 63) / 64;  // 782
    // hop 1: gather h0(fp8) -> agg; h1 = sigmoid(x@W0 + agg@V0) -> fp8 only
    k_agg<<<(N_NODES + 3) / 4, 256, 0, stream>>>(h8, edh, offs, alphas, aggcb);
    k_mm<<<MMBLK, 256, 0, stream>>>(xb, WsT, aggcb, VsT, h8, nullptr, N_NODES, DIN, DOUT);
    // hop 2: gather h1(fp8) -> agg; h2 = sigmoid(x@W1 + agg@V1) -> bf16 (for loss)
    k_agg<<<(N_NODES + 3) / 4, 256, 0, stream>>>(h8, edh, offs, alphas + NDEV, aggcb);
    k_mm<<<MMBLK, 256, 0, stream>>>(xb, WsT + (size_t)DOUT * DIN, aggcb,
                                    VsT + (size_t)DOUT * DOUT, nullptr, hbf,
                                    N_NODES, DIN, DOUT);

    k_loss<<<LOSS_BLOCKS, 256, 0, stream>>>(hbf, label, idx, u, Wc, bb, blockpart, NMASK);
    k_final<<<1, 256, 0, stream>>>(blockpart, out, LOSS_BLOCKS);
}

// Round 15
// 181.288 us; speedup vs baseline: 14.5329x; 1.0474x over previous
//
#include <hip/hip_runtime.h>
#include <hip/hip_bf16.h>

#define N_NODES 50000
#define DIN     256
#define DOUT    128
#define NCLS    2
#define NHOP    2
#define NDEV    3
#define EDG     500000
#define TE      (NDEV*EDG)
#define NMASK   10000
#define LOSS_BLOCKS 2500             // one masked node per wave

#define BUCK    128
#define NBUCK   391                  // ceil(50000/128)
#define CH      2048                 // edges per binning block
#define NBLKA   733                  // ceil(TE/CH)
#define BHN     (NBUCK*NBLKA)        // 286,603
#define SCT     512
#define SCANBLKS ((BHN + SCT - 1) / SCT)   // 560

typedef __attribute__((ext_vector_type(8))) short bf16x8;   // 8 bf16 = 4 VGPRs
typedef __attribute__((ext_vector_type(4))) float f32x4;
typedef __attribute__((ext_vector_type(2))) float f32x2;

__device__ __forceinline__ float softplusf(float a) {
    return fmaxf(a, 0.f) + log1pf(expf(-fabsf(a)));
}

// fp8 e4m3 (OCP on gfx950) helpers via HW pack/unpack
__device__ __forceinline__ f32x2 fp8lo(unsigned g) {
    return __builtin_amdgcn_cvt_pk_f32_fp8(g, false);
}
__device__ __forceinline__ f32x2 fp8hi(unsigned g) {
    return __builtin_amdgcn_cvt_pk_f32_fp8(g, true);
}
__device__ __forceinline__ unsigned char fp8enc1(float v) {
    return (unsigned char)(__builtin_amdgcn_cvt_pk_fp8_f32(v, v, 0, false) & 0xFF);
}

// ---------------- bucket-binned CSR build (write-amp ~1x) ----------------

__global__ __launch_bounds__(256) void k_bhist(const int* __restrict__ dst,
                                               int* __restrict__ bh) {
    __shared__ int hist[NBUCK];
    int blk = blockIdx.x, tid = threadIdx.x;
    for (int i = tid; i < NBUCK; i += 256) hist[i] = 0;
    __syncthreads();
    int base = blk * CH;
    int lim = min(base + CH, TE);
    for (int i = base + tid; i < lim; i += 256) atomicAdd(&hist[dst[i] >> 7], 1);
    __syncthreads();
    for (int i = tid; i < NBUCK; i += 256) bh[(size_t)i * NBLKA + blk] = hist[i];
}

__global__ __launch_bounds__(SCT) void k_scanA(const int* __restrict__ in,
                                               int* __restrict__ out,
                                               int* __restrict__ bsums, int n) {
    __shared__ int s[SCT];
    int tid = threadIdx.x, gid = blockIdx.x * SCT + tid;
    int v = (gid < n) ? in[gid] : 0;
    s[tid] = v; __syncthreads();
    for (int o = 1; o < SCT; o <<= 1) {
        int t = (tid >= o) ? s[tid - o] : 0;
        __syncthreads();
        s[tid] += t;
        __syncthreads();
    }
    if (gid < n) out[gid] = s[tid] - v;          // exclusive
    if (tid == SCT - 1) bsums[blockIdx.x] = s[SCT - 1];
}

// single-block carry-looped exclusive scan (handles nb > SCT)
__global__ __launch_bounds__(SCT) void k_scanB(int* __restrict__ bsums, int nb) {
    __shared__ int s[SCT];
    int tid = threadIdx.x;
    int carry = 0;
    for (int base = 0; base < nb; base += SCT) {
        int v = (base + tid < nb) ? bsums[base + tid] : 0;
        s[tid] = v; __syncthreads();
        for (int o = 1; o < SCT; o <<= 1) {
            int t = (tid >= o) ? s[tid - o] : 0;
            __syncthreads();
            s[tid] += t;
            __syncthreads();
        }
        if (base + tid < nb) bsums[base + tid] = s[tid] - v + carry;
        carry += s[SCT - 1];
        __syncthreads();
    }
}

__global__ __launch_bounds__(SCT) void k_scanC(int* __restrict__ out,
                                               const int* __restrict__ bsums, int n) {
    int gid = blockIdx.x * SCT + threadIdx.x;
    if (gid < n) out[gid] += bsums[blockIdx.x];
}

// merged: bin edges into bucket-grouped array (blocks < NBLKA) | prep conversions
// (blocks >= NBLKA). Independent buffers -> safe to run in one dispatch.
#define PREP_A (N_NODES * DOUT / 4)          // float4 units of h0
#define PREP_B (N_NODES * DIN / 2)           // float2 units of x
#define PREP_W (NHOP * (DIN * DOUT + DOUT * DOUT))
#define PREPBLK ((PREP_A + PREP_B + PREP_W + 255) / 256)
__global__ __launch_bounds__(256) void k_bbin_prep(const int* __restrict__ src,
                                                   const int* __restrict__ dst,
                                                   const float* __restrict__ vals,
                                                   const int* __restrict__ sc,
                                                   uint2* __restrict__ ebkt,
                                                   const float* __restrict__ h0,
                                                   unsigned char* __restrict__ h8,
                                                   const float* __restrict__ x,
                                                   __hip_bfloat16* __restrict__ xb,
                                                   const float* __restrict__ Ws,
                                                   const float* __restrict__ Vs,
                                                   __hip_bfloat16* __restrict__ WsT,
                                                   __hip_bfloat16* __restrict__ VsT) {
    __shared__ int cur[NBUCK];
    int blk = blockIdx.x, tid = threadIdx.x;
    if (blk < NBLKA) {
        // ---- binning ----
        for (int i = tid; i < NBUCK; i += 256) cur[i] = sc[(size_t)i * NBLKA + blk];
        __syncthreads();
        int base = blk * CH;
        int lim = min(base + CH, TE);
        for (int i = base + tid; i < lim; i += 256) {
            int d = i / EDG;
            int n = dst[i];
            int bu = n >> 7;
            int pos = atomicAdd(&cur[bu], 1);
            ebkt[pos] = make_uint2((unsigned)src[i] | ((unsigned)d << 16) |
                                   ((unsigned)(n & 127) << 18),
                                   __float_as_uint(vals[i]));
        }
    } else {
        // ---- prep ----
        int i = (blk - NBLKA) * 256 + tid;
        if (i < PREP_A) {
            float4 f = ((const float4*)h0)[i];
            int r = 0;
            r = __builtin_amdgcn_cvt_pk_fp8_f32(f.x, f.y, r, false);
            r = __builtin_amdgcn_cvt_pk_fp8_f32(f.z, f.w, r, true);
            ((unsigned*)h8)[i] = (unsigned)r;
        } else if (i < PREP_A + PREP_B) {
            int j = i - PREP_A;
            float2 f = ((const float2*)x)[j];
            __hip_bfloat162 b;
            b.x = __float2bfloat16(f.x);
            b.y = __float2bfloat16(f.y);
            ((__hip_bfloat162*)xb)[j] = b;
        } else {
            int j = i - PREP_A - PREP_B;
            if (j < NHOP * DIN * DOUT) {
                int hop = j / (DIN * DOUT);
                int r = j % (DIN * DOUT);
                int k = r >> 7, n = r & 127;
                WsT[(size_t)hop * DOUT * DIN + (size_t)n * DIN + k] = __float2bfloat16(Ws[j]);
            } else if (j < PREP_W) {
                int j2 = j - NHOP * DIN * DOUT;
                int hop = j2 / (DOUT * DOUT);
                int r = j2 % (DOUT * DOUT);
                int k = r >> 7, n = r & 127;
                VsT[(size_t)hop * DOUT * DOUT + (size_t)n * DOUT + k] = __float2bfloat16(Vs[j2]);
            }
        }
    }
}

// per-bucket counting sort by node; emits {src|dev<<16, val} edge array + offsets
__global__ __launch_bounds__(256) void k_bsort(const uint2* __restrict__ ebkt,
                                               const int* __restrict__ sc,
                                               uint2* __restrict__ edh,
                                               int* __restrict__ offs) {
    __shared__ int cnt[BUCK], start[BUCK + 1], cur[BUCK];
    int b = blockIdx.x, tid = threadIdx.x;
    int beg = sc[(size_t)b * NBLKA];
    int end = (b + 1 < NBUCK) ? sc[(size_t)(b + 1) * NBLKA] : TE;
    if (tid < BUCK) { cnt[tid] = 0; cur[tid] = 0; }
    __syncthreads();
    for (int e = beg + tid; e < end; e += 256)
        atomicAdd(&cnt[(ebkt[e].x >> 18) & 127], 1);
    __syncthreads();
    if (tid == 0) {
        int acc = 0;
        for (int i = 0; i < BUCK; ++i) { start[i] = acc; acc += cnt[i]; }
        start[BUCK] = acc;
    }
    __syncthreads();
    if (tid < BUCK) {
        int n = b * BUCK + tid;
        if (n < N_NODES) offs[n] = beg + start[tid];
    }
    if (b == 0 && tid == 255) offs[N_NODES] = TE;
    for (int e = beg + tid; e < end; e += 256) {
        uint2 v = ebkt[e];
        int dl = (v.x >> 18) & 127;
        int pos = beg + start[dl] + atomicAdd(&cur[dl], 1);
        edh[pos] = make_uint2(v.x & 0x3FFFFu, v.y);   // src | dev<<16, val
    }
}

// ---------------- sparse aggregation: one wave per node, 8 edges/iter --------------
// lane = grp(0..7)*8 + cw(0..7). Software-pipelined: next batch's edh meta is loaded
// one iteration ahead, so the gather (which depends on meta) issues at iter start —
// one memory round-trip per iteration instead of two.
__global__ __launch_bounds__(256) void k_agg(const unsigned char* __restrict__ h8,
                                             const uint2* __restrict__ edh,
                                             const int* __restrict__ offs,
                                             const float* __restrict__ alpha_hop,
                                             __hip_bfloat16* __restrict__ aggcb) {
    int wid = threadIdx.x >> 6;
    int lane = threadIdx.x & 63;
    int n = blockIdx.x * 4 + wid;
    if (n >= N_NODES) return;
    float a0 = alpha_hop[0], a1 = alpha_hop[1], a2 = alpha_hop[2];
    int grp = lane >> 3;         // edge slot within the 8-edge batch
    int cw = lane & 7;           // 16-byte chunk of the 128B fp8 row
    int beg = offs[n], end = offs[n + 1];
    float a[16];
#pragma unroll
    for (int j = 0; j < 16; ++j) a[j] = 0.f;

    int e = beg;
    uint2 q = make_uint2(0u, 0u);
    if (e < end) {
        int rem = end - e;
        q = edh[e + (grp < rem ? grp : 0)];
    }
    while (e < end) {
        int enext = e + 8;
        uint2 qn = q;
        if (enext < end) {
            int remn = end - enext;
            qn = edh[enext + (grp < remn ? grp : 0)];   // prefetch next batch meta
        }
        int rem = end - e;
        int d = (q.x >> 16) & 3;
        float wt = __uint_as_float(q.y) * (d == 0 ? a0 : (d == 1 ? a1 : a2));
        wt = (grp < rem) ? wt : 0.f;
        uint4 g = *(const uint4*)(h8 + (size_t)(q.x & 0xFFFFu) * DOUT + cw * 16);
#pragma unroll
        for (int wv = 0; wv < 4; ++wv) {
            unsigned gw = (&g.x)[wv];
            f32x2 lo = fp8lo(gw), hi = fp8hi(gw);
            a[wv * 4 + 0] += wt * lo[0];
            a[wv * 4 + 1] += wt * lo[1];
            a[wv * 4 + 2] += wt * hi[0];
            a[wv * 4 + 3] += wt * hi[1];
        }
        q = qn;
        e = enext;
    }
    // fold the 8 edge-groups (lane bits 3,4,5)
#pragma unroll
    for (int j = 0; j < 16; ++j) {
        a[j] += __shfl_xor(a[j], 8, 64);
        a[j] += __shfl_xor(a[j], 16, 64);
        a[j] += __shfl_xor(a[j], 32, 64);
    }
    if (grp == 0) {               // lanes 0..7 write cols cw*16 .. cw*16+15
        union { __hip_bfloat16 h[8]; uint4 u; } pk0, pk1;
#pragma unroll
        for (int j = 0; j < 8; ++j) {
            pk0.h[j] = __float2bfloat16(a[j]);
            pk1.h[j] = __float2bfloat16(a[8 + j]);
        }
        *(uint4*)(aggcb + (size_t)n * DOUT + cw * 16) = pk0.u;
        *(uint4*)(aggcb + (size_t)n * DOUT + cw * 16 + 8) = pk1.u;
    }
}

// ---------------- fused MFMA GEMM: h = sigmoid(A1@B1 + A2@B2), bf16 in --------------
// BM=64 tile (782 blocks -> ~3 blocks/CU, balanced), 4 waves (2x2), wave = 32x64 via
// 2x4 mfma_f32_16x16x32_bf16 frags. LDS-staged A and B (verified-better vs direct).
__global__ __launch_bounds__(256) void k_mm(const __hip_bfloat16* __restrict__ A1,
                                            const __hip_bfloat16* __restrict__ BT1,
                                            const __hip_bfloat16* __restrict__ A2,
                                            const __hip_bfloat16* __restrict__ BT2,
                                            unsigned char* __restrict__ C8,
                                            __hip_bfloat16* __restrict__ Cbf,
                                            int M, int K1, int K2) {
    __shared__ short As[64][40];    // stride 40: bank-starts spread, <=2-way (free)
    __shared__ short Bs[128][40];
    int tid = threadIdx.x;
    int lane = tid & 63;
    int w = tid >> 6;
    int wr = (w >> 1) * 32, wc = (w & 1) * 64;
    int lr = lane & 15, kg = lane >> 4;
    int row0 = blockIdx.x * 64;

    f32x4 acc[2][4];
#pragma unroll
    for (int mi = 0; mi < 2; ++mi)
#pragma unroll
        for (int ni = 0; ni < 4; ++ni) acc[mi][ni] = (f32x4){0.f, 0.f, 0.f, 0.f};

#pragma unroll
    for (int seg = 0; seg < 2; ++seg) {
        const __hip_bfloat16* A = seg ? A2 : A1;
        const __hip_bfloat16* BT = seg ? BT2 : BT1;
        int K = seg ? K2 : K1;
        for (int k0 = 0; k0 < K; k0 += 32) {
            {   // stage A tile: 256 x 16B chunks, 1 per thread
                int r = tid >> 2, kc = (tid & 3) * 8;
                bf16x8 g = {};
                int gr = row0 + r;
                if (gr < M) g = *(const bf16x8*)(A + (size_t)gr * K + k0 + kc);
                *(bf16x8*)&As[r][kc] = g;
            }
#pragma unroll
            for (int j = 0; j < 2; ++j) {           // stage BT tile: 512 chunks
                int c = tid + j * 256;
                int r = c >> 2, kc = (c & 3) * 8;
                *(bf16x8*)&Bs[r][kc] = *(const bf16x8*)(BT + (size_t)r * K + k0 + kc);
            }
            __syncthreads();
            bf16x8 af[2], bfr[4];
#pragma unroll
            for (int i = 0; i < 2; ++i)
                af[i] = *(const bf16x8*)&As[wr + i * 16 + lr][kg * 8];
#pragma unroll
            for (int i = 0; i < 4; ++i)
                bfr[i] = *(const bf16x8*)&Bs[wc + i * 16 + lr][kg * 8];
#pragma unroll
            for (int mi = 0; mi < 2; ++mi)
#pragma unroll
                for (int ni = 0; ni < 4; ++ni)
                    acc[mi][ni] = __builtin_amdgcn_mfma_f32_16x16x32_bf16(
                        af[mi], bfr[ni], acc[mi][ni], 0, 0, 0);
            __syncthreads();
        }
    }

#pragma unroll
    for (int mi = 0; mi < 2; ++mi) {
#pragma unroll
        for (int r = 0; r < 4; ++r) {
            int row = row0 + wr + mi * 16 + kg * 4 + r;   // C/D: row=(lane>>4)*4+reg
            if (row < M) {
#pragma unroll
                for (int ni = 0; ni < 4; ++ni) {
                    int col = wc + ni * 16 + lr;          // C/D: col=lane&15
                    float v = acc[mi][ni][r];
                    v = 1.f / (1.f + __expf(-v));
                    if (C8)  C8[(size_t)row * DOUT + col] = fp8enc1(v);
                    if (Cbf) Cbf[(size_t)row * DOUT + col] = __float2bfloat16(v);
                }
            }
        }
    }
}

// ---------------- masked loss + accuracy: one node per wave ----------------
__global__ __launch_bounds__(256) void k_loss(const __hip_bfloat16* __restrict__ h,
                                              const float* __restrict__ label,
                                              const int* __restrict__ idx,
                                              const float* __restrict__ u,
                                              const float* __restrict__ Wc,
                                              const float* __restrict__ bb,
                                              float* __restrict__ blockpart, int Mtot) {
    __shared__ float sl[4], sc2[4];
    int wid = threadIdx.x >> 6;
    int lane = threadIdx.x & 63;
    int w = blockIdx.x * 4 + wid;
    float lsum = 0.f, csum = 0.f;
    if (w < Mtot) {
        int node = idx[w];
        float v0 = __bfloat162float(h[(size_t)node * DOUT + lane]);
        float v1 = __bfloat162float(h[(size_t)node * DOUT + 64 + lane]);
        float ps = v0 * u[lane] + v1 * u[64 + lane];
        float p0 = v0 * Wc[lane * 2 + 0] + v1 * Wc[(lane + 64) * 2 + 0];
        float p1 = v0 * Wc[lane * 2 + 1] + v1 * Wc[(lane + 64) * 2 + 1];
#pragma unroll
        for (int o = 32; o > 0; o >>= 1) {
            ps += __shfl_xor(ps, o, 64);
            p0 += __shfl_xor(p0, o, 64);
            p1 += __shfl_xor(p1, o, 64);
        }
        if (lane == 0) {
            float y0 = label[(size_t)node * NCLS + 0];
            float y1 = label[(size_t)node * NCLS + 1];
            lsum = softplusf(-(y0 * ps)) + softplusf(-(y1 * ps));
            float l0 = p0 + bb[0], l1 = p1 + bb[1];
            int pred = (l1 > l0) ? 1 : 0;
            int truth = (y1 > y0) ? 1 : 0;
            csum = (pred == truth) ? 1.f : 0.f;
        }
    }
    if (lane == 0) { sl[wid] = lsum; sc2[wid] = csum; }
    __syncthreads();
    if (threadIdx.x == 0) {
        blockpart[blockIdx.x * 2 + 0] = sl[0] + sl[1] + sl[2] + sl[3];
        blockpart[blockIdx.x * 2 + 1] = sc2[0] + sc2[1] + sc2[2] + sc2[3];
    }
}

__global__ __launch_bounds__(256) void k_final(const float* __restrict__ bp,
                                               float* __restrict__ out, int nb) {
    __shared__ float sl[256], sc2[256];
    int t = threadIdx.x;
    float l = 0.f, c = 0.f;
    for (int i = t; i < nb; i += 256) { l += bp[i * 2]; c += bp[i * 2 + 1]; }
    sl[t] = l; sc2[t] = c;
    __syncthreads();
    for (int o = 128; o > 0; o >>= 1) {
        if (t < o) { sl[t] += sl[t + o]; sc2[t] += sc2[t + o]; }
        __syncthreads();
    }
    if (t == 0) { out[0] = sl[0]; out[1] = sc2[0] * (1.0f / NMASK); }
}

// ---------------- launch ----------------
extern "C" void kernel_launch(void* const* d_in, const int* in_sizes, int n_in,
                              void* d_out, int out_size, void* d_ws, size_t ws_size,
                              hipStream_t stream) {
    const float* x      = (const float*)d_in[0];
    const float* label  = (const float*)d_in[1];
    const int*   idx    = (const int*)d_in[2];
    const int*   src    = (const int*)d_in[3];
    const int*   dst    = (const int*)d_in[4];
    const float* vals   = (const float*)d_in[5];
    const float* h0     = (const float*)d_in[6];
    const float* Ws     = (const float*)d_in[7];
    const float* Vs     = (const float*)d_in[8];
    const float* alphas = (const float*)d_in[9];
    const float* Wc     = (const float*)d_in[10];
    const float* bb     = (const float*)d_in[11];
    const float* u      = (const float*)d_in[12];
    float* out = (float*)d_out;

    // fully un-aliased layout (~92 MB; ws is ~268 MB per harness fill size)
    char* p = (char*)d_ws;
    __hip_bfloat16* aggcb = (__hip_bfloat16*)p; p += (size_t)N_NODES * DOUT * 2;  // 12.8 MB
    __hip_bfloat16* xb    = (__hip_bfloat16*)p; p += (size_t)N_NODES * DIN * 2;   // 25.6 MB
    unsigned char*  h8    = (unsigned char*)p;  p += (size_t)N_NODES * DOUT;      // 6.4 MB
    __hip_bfloat16* hbf   = (__hip_bfloat16*)p; p += (size_t)N_NODES * DOUT * 2;  // 12.8 MB
    uint2*          edh   = (uint2*)p;          p += (size_t)TE * 8;              // 12 MB
    uint2*          ebkt  = (uint2*)p;          p += (size_t)TE * 8;              // 12 MB
    int*            offs  = (int*)p;            p += 200064 * 4;                  // ~0.8 MB
    int*            bh    = (int*)p;            p += (size_t)BHN * 4;             // 1.15 MB
    int*            sc    = (int*)p;            p += (size_t)BHN * 4;             // 1.15 MB
    int*            bsums = (int*)p;            p += 4096 * 4;
    __hip_bfloat16* WsT   = (__hip_bfloat16*)p; p += (size_t)NHOP * DOUT * DIN * 2;  // 128 KB
    __hip_bfloat16* VsT   = (__hip_bfloat16*)p; p += (size_t)NHOP * DOUT * DOUT * 2; // 64 KB
    float*          blockpart = (float*)p;      p += LOSS_BLOCKS * 2 * 4;         // 20 KB

    // bucket-binned CSR build; prep (h0->fp8, x->bf16, W/V transpose) hidden under bbin
    k_bhist<<<NBLKA, 256, 0, stream>>>(dst, bh);
    k_scanA<<<SCANBLKS, SCT, 0, stream>>>(bh, sc, bsums, BHN);
    k_scanB<<<1, SCT, 0, stream>>>(bsums, SCANBLKS);
    k_scanC<<<SCANBLKS, SCT, 0, stream>>>(sc, bsums, BHN);
    k_bbin_prep<<<NBLKA + PREPBLK, 256, 0, stream>>>(src, dst, vals, sc, ebkt,
                                                     h0, h8, x, xb, Ws, Vs, WsT, VsT);
    k_bsort<<<NBUCK, 256, 0, stream>>>(ebkt, sc, edh, offs);

    const int MMBLK = (N_NODES + 63) / 64;  // 782
    // hop 1: gather h0(fp8) -> agg; h1 = sigmoid(x@W0 + agg@V0) -> fp8 only
    k_agg<<<(N_NODES + 3) / 4, 256, 0, stream>>>(h8, edh, offs, alphas, aggcb);
    k_mm<<<MMBLK, 256, 0, stream>>>(xb, WsT, aggcb, VsT, h8, nullptr, N_NODES, DIN, DOUT);
    // hop 2: gather h1(fp8) -> agg; h2 = sigmoid(x@W1 + agg@V1) -> bf16 (for loss)
    k_agg<<<(N_NODES + 3) / 4, 256, 0, stream>>>(h8, edh, offs, alphas + NDEV, aggcb);
    k_mm<<<MMBLK, 256, 0, stream>>>(xb, WsT + (size_t)DOUT * DIN, aggcb,
                                    VsT + (size_t)DOUT * DOUT, nullptr, hbf,
                                    N_NODES, DIN, DOUT);

    k_loss<<<LOSS_BLOCKS, 256, 0, stream>>>(hbf, label, idx, u, Wc, bb, blockpart, NMASK);
    k_final<<<1, 256, 0, stream>>>(blockpart, out, LOSS_BLOCKS);
}

// Round 16
// 174.435 us; speedup vs baseline: 15.1039x; 1.0393x over previous
//
#include <hip/hip_runtime.h>
#include <hip/hip_bf16.h>

#define N_NODES 50000
#define DIN     256
#define DOUT    128
#define NCLS    2
#define NHOP    2
#define NDEV    3
#define EDG     500000
#define TE      (NDEV*EDG)
#define NMASK   10000
#define LOSS_BLOCKS 2500             // one masked node per wave

#define BUCK    256
#define NBUCK   196                  // ceil(50000/256)
#define CH      4096                 // edges per binning block
#define NBLKA   367                  // ceil(TE/CH)
#define BHN     (NBUCK*NBLKA)        // 71,932
#define SCT     512
#define SCANBLKS ((BHN + SCT - 1) / SCT)   // 141

typedef __attribute__((ext_vector_type(8))) short bf16x8;   // 8 bf16 = 4 VGPRs
typedef __attribute__((ext_vector_type(4))) float f32x4;
typedef __attribute__((ext_vector_type(2))) float f32x2;

__device__ __forceinline__ float softplusf(float a) {
    return fmaxf(a, 0.f) + log1pf(expf(-fabsf(a)));
}

// fp8 e4m3 (OCP on gfx950) helpers via HW pack/unpack
__device__ __forceinline__ f32x2 fp8lo(unsigned g) {
    return __builtin_amdgcn_cvt_pk_f32_fp8(g, false);
}
__device__ __forceinline__ f32x2 fp8hi(unsigned g) {
    return __builtin_amdgcn_cvt_pk_f32_fp8(g, true);
}
__device__ __forceinline__ unsigned char fp8enc1(float v) {
    return (unsigned char)(__builtin_amdgcn_cvt_pk_fp8_f32(v, v, 0, false) & 0xFF);
}

// ---------------- bucket-binned CSR build (write-amp ~1x) ----------------

__global__ __launch_bounds__(256) void k_bhist(const int* __restrict__ dst,
                                               int* __restrict__ bh) {
    __shared__ int hist[NBUCK];
    int blk = blockIdx.x, tid = threadIdx.x;
    for (int i = tid; i < NBUCK; i += 256) hist[i] = 0;
    __syncthreads();
    int base = blk * CH;
    int lim = min(base + CH, TE);
    for (int i = base + tid; i < lim; i += 256) atomicAdd(&hist[dst[i] >> 8], 1);
    __syncthreads();
    for (int i = tid; i < NBUCK; i += 256) bh[(size_t)i * NBLKA + blk] = hist[i];
}

__global__ __launch_bounds__(SCT) void k_scanA(const int* __restrict__ in,
                                               int* __restrict__ out,
                                               int* __restrict__ bsums, int n) {
    __shared__ int s[SCT];
    int tid = threadIdx.x, gid = blockIdx.x * SCT + tid;
    int v = (gid < n) ? in[gid] : 0;
    s[tid] = v; __syncthreads();
    for (int o = 1; o < SCT; o <<= 1) {
        int t = (tid >= o) ? s[tid - o] : 0;
        __syncthreads();
        s[tid] += t;
        __syncthreads();
    }
    if (gid < n) out[gid] = s[tid] - v;          // exclusive
    if (tid == SCT - 1) bsums[blockIdx.x] = s[SCT - 1];
}

// single-block carry-looped exclusive scan (handles nb > SCT)
__global__ __launch_bounds__(SCT) void k_scanB(int* __restrict__ bsums, int nb) {
    __shared__ int s[SCT];
    int tid = threadIdx.x;
    int carry = 0;
    for (int base = 0; base < nb; base += SCT) {
        int v = (base + tid < nb) ? bsums[base + tid] : 0;
        s[tid] = v; __syncthreads();
        for (int o = 1; o < SCT; o <<= 1) {
            int t = (tid >= o) ? s[tid - o] : 0;
            __syncthreads();
            s[tid] += t;
            __syncthreads();
        }
        if (base + tid < nb) bsums[base + tid] = s[tid] - v + carry;
        carry += s[SCT - 1];
        __syncthreads();
    }
}

__global__ __launch_bounds__(SCT) void k_scanC(int* __restrict__ out,
                                               const int* __restrict__ bsums, int n) {
    int gid = blockIdx.x * SCT + threadIdx.x;
    if (gid < n) out[gid] += bsums[blockIdx.x];
}

// merged: bin edges into bucket-grouped array (blocks < NBLKA) | prep conversions
// (blocks >= NBLKA). Independent buffers -> safe to run in one dispatch.
#define PREP_A (N_NODES * DOUT / 4)          // float4 units of h0
#define PREP_B (N_NODES * DIN / 2)           // float2 units of x
#define PREP_W (NHOP * (DIN * DOUT + DOUT * DOUT))
#define PREPBLK ((PREP_A + PREP_B + PREP_W + 255) / 256)
__global__ __launch_bounds__(256) void k_bbin_prep(const int* __restrict__ src,
                                                   const int* __restrict__ dst,
                                                   const float* __restrict__ vals,
                                                   const int* __restrict__ sc,
                                                   uint2* __restrict__ ebkt,
                                                   const float* __restrict__ h0,
                                                   unsigned char* __restrict__ h8,
                                                   const float* __restrict__ x,
                                                   __hip_bfloat16* __restrict__ xb,
                                                   const float* __restrict__ Ws,
                                                   const float* __restrict__ Vs,
                                                   __hip_bfloat16* __restrict__ WsT,
                                                   __hip_bfloat16* __restrict__ VsT) {
    __shared__ int cur[NBUCK];
    int blk = blockIdx.x, tid = threadIdx.x;
    if (blk < NBLKA) {
        // ---- binning: runs of ~21 edges (168B) per bucket per block ----
        for (int i = tid; i < NBUCK; i += 256) cur[i] = sc[(size_t)i * NBLKA + blk];
        __syncthreads();
        int base = blk * CH;
        int lim = min(base + CH, TE);
        for (int i = base + tid; i < lim; i += 256) {
            int d = i / EDG;
            int n = dst[i];
            int bu = n >> 8;
            int pos = atomicAdd(&cur[bu], 1);
            ebkt[pos] = make_uint2((unsigned)src[i] | ((unsigned)d << 16) |
                                   ((unsigned)(n & 255) << 18),
                                   __float_as_uint(vals[i]));
        }
    } else {
        // ---- prep ----
        int i = (blk - NBLKA) * 256 + tid;
        if (i < PREP_A) {
            float4 f = ((const float4*)h0)[i];
            int r = 0;
            r = __builtin_amdgcn_cvt_pk_fp8_f32(f.x, f.y, r, false);
            r = __builtin_amdgcn_cvt_pk_fp8_f32(f.z, f.w, r, true);
            ((unsigned*)h8)[i] = (unsigned)r;
        } else if (i < PREP_A + PREP_B) {
            int j = i - PREP_A;
            float2 f = ((const float2*)x)[j];
            __hip_bfloat162 b;
            b.x = __float2bfloat16(f.x);
            b.y = __float2bfloat16(f.y);
            ((__hip_bfloat162*)xb)[j] = b;
        } else {
            int j = i - PREP_A - PREP_B;
            if (j < NHOP * DIN * DOUT) {
                int hop = j / (DIN * DOUT);
                int r = j % (DIN * DOUT);
                int k = r >> 7, n = r & 127;
                WsT[(size_t)hop * DOUT * DIN + (size_t)n * DIN + k] = __float2bfloat16(Ws[j]);
            } else if (j < PREP_W) {
                int j2 = j - NHOP * DIN * DOUT;
                int hop = j2 / (DOUT * DOUT);
                int r = j2 % (DOUT * DOUT);
                int k = r >> 7, n = r & 127;
                VsT[(size_t)hop * DOUT * DOUT + (size_t)n * DOUT + k] = __float2bfloat16(Vs[j2]);
            }
        }
    }
}

// per-bucket counting sort by node (512 threads/block to offset fewer blocks);
// emits {src|dev<<16, val} edge array + per-node offsets
__global__ __launch_bounds__(512) void k_bsort(const uint2* __restrict__ ebkt,
                                               const int* __restrict__ sc,
                                               uint2* __restrict__ edh,
                                               int* __restrict__ offs) {
    __shared__ int cnt[BUCK], start[BUCK + 1], cur[BUCK];
    int b = blockIdx.x, tid = threadIdx.x;
    int beg = sc[(size_t)b * NBLKA];
    int end = (b + 1 < NBUCK) ? sc[(size_t)(b + 1) * NBLKA] : TE;
    if (tid < BUCK) { cnt[tid] = 0; cur[tid] = 0; }
    __syncthreads();
    for (int e = beg + tid; e < end; e += 512)
        atomicAdd(&cnt[(ebkt[e].x >> 18) & 255], 1);
    __syncthreads();
    if (tid == 0) {
        int acc = 0;
        for (int i = 0; i < BUCK; ++i) { start[i] = acc; acc += cnt[i]; }
        start[BUCK] = acc;
    }
    __syncthreads();
    if (tid < BUCK) {
        int n = b * BUCK + tid;
        if (n < N_NODES) offs[n] = beg + start[tid];
    }
    if (b == 0 && tid == 511) offs[N_NODES] = TE;
    for (int e = beg + tid; e < end; e += 512) {
        uint2 v = ebkt[e];
        int dl = (v.x >> 18) & 255;
        int pos = beg + start[dl] + atomicAdd(&cur[dl], 1);
        edh[pos] = make_uint2(v.x & 0x3FFFFu, v.y);   // src | dev<<16, val
    }
}

// ---------------- sparse aggregation: one wave per node, 8 edges/iter --------------
// lane = grp(0..7)*8 + cw(0..7). Software-pipelined: next batch's edh meta is loaded
// one iteration ahead, so the gather (which depends on meta) issues at iter start.
__global__ __launch_bounds__(256) void k_agg(const unsigned char* __restrict__ h8,
                                             const uint2* __restrict__ edh,
                                             const int* __restrict__ offs,
                                             const float* __restrict__ alpha_hop,
                                             __hip_bfloat16* __restrict__ aggcb) {
    int wid = threadIdx.x >> 6;
    int lane = threadIdx.x & 63;
    int n = blockIdx.x * 4 + wid;
    if (n >= N_NODES) return;
    float a0 = alpha_hop[0], a1 = alpha_hop[1], a2 = alpha_hop[2];
    int grp = lane >> 3;         // edge slot within the 8-edge batch
    int cw = lane & 7;           // 16-byte chunk of the 128B fp8 row
    int beg = offs[n], end = offs[n + 1];
    float a[16];
#pragma unroll
    for (int j = 0; j < 16; ++j) a[j] = 0.f;

    int e = beg;
    uint2 q = make_uint2(0u, 0u);
    if (e < end) {
        int rem = end - e;
        q = edh[e + (grp < rem ? grp : 0)];
    }
    while (e < end) {
        int enext = e + 8;
        uint2 qn = q;
        if (enext < end) {
            int remn = end - enext;
            qn = edh[enext + (grp < remn ? grp : 0)];   // prefetch next batch meta
        }
        int rem = end - e;
        int d = (q.x >> 16) & 3;
        float wt = __uint_as_float(q.y) * (d == 0 ? a0 : (d == 1 ? a1 : a2));
        wt = (grp < rem) ? wt : 0.f;
        uint4 g = *(const uint4*)(h8 + (size_t)(q.x & 0xFFFFu) * DOUT + cw * 16);
#pragma unroll
        for (int wv = 0; wv < 4; ++wv) {
            unsigned gw = (&g.x)[wv];
            f32x2 lo = fp8lo(gw), hi = fp8hi(gw);
            a[wv * 4 + 0] += wt * lo[0];
            a[wv * 4 + 1] += wt * lo[1];
            a[wv * 4 + 2] += wt * hi[0];
            a[wv * 4 + 3] += wt * hi[1];
        }
        q = qn;
        e = enext;
    }
    // fold the 8 edge-groups (lane bits 3,4,5)
#pragma unroll
    for (int j = 0; j < 16; ++j) {
        a[j] += __shfl_xor(a[j], 8, 64);
        a[j] += __shfl_xor(a[j], 16, 64);
        a[j] += __shfl_xor(a[j], 32, 64);
    }
    if (grp == 0) {               // lanes 0..7 write cols cw*16 .. cw*16+15
        union { __hip_bfloat16 h[8]; uint4 u; } pk0, pk1;
#pragma unroll
        for (int j = 0; j < 8; ++j) {
            pk0.h[j] = __float2bfloat16(a[j]);
            pk1.h[j] = __float2bfloat16(a[8 + j]);
        }
        *(uint4*)(aggcb + (size_t)n * DOUT + cw * 16) = pk0.u;
        *(uint4*)(aggcb + (size_t)n * DOUT + cw * 16 + 8) = pk1.u;
    }
}

// ---------------- fused MFMA GEMM: h = sigmoid(A1@B1 + A2@B2), bf16 in --------------
// BM=64 tile (782 blocks -> ~3 blocks/CU, balanced), 4 waves (2x2), wave = 32x64 via
// 2x4 mfma_f32_16x16x32_bf16 frags. LDS-staged A and B (verified-better vs direct).
__global__ __launch_bounds__(256) void k_mm(const __hip_bfloat16* __restrict__ A1,
                                            const __hip_bfloat16* __restrict__ BT1,
                                            const __hip_bfloat16* __restrict__ A2,
                                            const __hip_bfloat16* __restrict__ BT2,
                                            unsigned char* __restrict__ C8,
                                            __hip_bfloat16* __restrict__ Cbf,
                                            int M, int K1, int K2) {
    __shared__ short As[64][40];    // stride 40: bank-starts spread, <=2-way (free)
    __shared__ short Bs[128][40];
    int tid = threadIdx.x;
    int lane = tid & 63;
    int w = tid >> 6;
    int wr = (w >> 1) * 32, wc = (w & 1) * 64;
    int lr = lane & 15, kg = lane >> 4;
    int row0 = blockIdx.x * 64;

    f32x4 acc[2][4];
#pragma unroll
    for (int mi = 0; mi < 2; ++mi)
#pragma unroll
        for (int ni = 0; ni < 4; ++ni) acc[mi][ni] = (f32x4){0.f, 0.f, 0.f, 0.f};

#pragma unroll
    for (int seg = 0; seg < 2; ++seg) {
        const __hip_bfloat16* A = seg ? A2 : A1;
        const __hip_bfloat16* BT = seg ? BT2 : BT1;
        int K = seg ? K2 : K1;
        for (int k0 = 0; k0 < K; k0 += 32) {
            {   // stage A tile: 256 x 16B chunks, 1 per thread
                int r = tid >> 2, kc = (tid & 3) * 8;
                bf16x8 g = {};
                int gr = row0 + r;
                if (gr < M) g = *(const bf16x8*)(A + (size_t)gr * K + k0 + kc);
                *(bf16x8*)&As[r][kc] = g;
            }
#pragma unroll
            for (int j = 0; j < 2; ++j) {           // stage BT tile: 512 chunks
                int c = tid + j * 256;
                int r = c >> 2, kc = (c & 3) * 8;
                *(bf16x8*)&Bs[r][kc] = *(const bf16x8*)(BT + (size_t)r * K + k0 + kc);
            }
            __syncthreads();
            bf16x8 af[2], bfr[4];
#pragma unroll
            for (int i = 0; i < 2; ++i)
                af[i] = *(const bf16x8*)&As[wr + i * 16 + lr][kg * 8];
#pragma unroll
            for (int i = 0; i < 4; ++i)
                bfr[i] = *(const bf16x8*)&Bs[wc + i * 16 + lr][kg * 8];
#pragma unroll
            for (int mi = 0; mi < 2; ++mi)
#pragma unroll
                for (int ni = 0; ni < 4; ++ni)
                    acc[mi][ni] = __builtin_amdgcn_mfma_f32_16x16x32_bf16(
                        af[mi], bfr[ni], acc[mi][ni], 0, 0, 0);
            __syncthreads();
        }
    }

#pragma unroll
    for (int mi = 0; mi < 2; ++mi) {
#pragma unroll
        for (int r = 0; r < 4; ++r) {
            int row = row0 + wr + mi * 16 + kg * 4 + r;   // C/D: row=(lane>>4)*4+reg
            if (row < M) {
#pragma unroll
                for (int ni = 0; ni < 4; ++ni) {
                    int col = wc + ni * 16 + lr;          // C/D: col=lane&15
                    float v = acc[mi][ni][r];
                    v = 1.f / (1.f + __expf(-v));
                    if (C8)  C8[(size_t)row * DOUT + col] = fp8enc1(v);
                    if (Cbf) Cbf[(size_t)row * DOUT + col] = __float2bfloat16(v);
                }
            }
        }
    }
}

// ---------------- masked loss + accuracy: one node per wave ----------------
__global__ __launch_bounds__(256) void k_loss(const __hip_bfloat16* __restrict__ h,
                                              const float* __restrict__ label,
                                              const int* __restrict__ idx,
                                              const float* __restrict__ u,
                                              const float* __restrict__ Wc,
                                              const float* __restrict__ bb,
                                              float* __restrict__ blockpart, int Mtot) {
    __shared__ float sl[4], sc2[4];
    int wid = threadIdx.x >> 6;
    int lane = threadIdx.x & 63;
    int w = blockIdx.x * 4 + wid;
    float lsum = 0.f, csum = 0.f;
    if (w < Mtot) {
        int node = idx[w];
        float v0 = __bfloat162float(h[(size_t)node * DOUT + lane]);
        float v1 = __bfloat162float(h[(size_t)node * DOUT + 64 + lane]);
        float ps = v0 * u[lane] + v1 * u[64 + lane];
        float p0 = v0 * Wc[lane * 2 + 0] + v1 * Wc[(lane + 64) * 2 + 0];
        float p1 = v0 * Wc[lane * 2 + 1] + v1 * Wc[(lane + 64) * 2 + 1];
#pragma unroll
        for (int o = 32; o > 0; o >>= 1) {
            ps += __shfl_xor(ps, o, 64);
            p0 += __shfl_xor(p0, o, 64);
            p1 += __shfl_xor(p1, o, 64);
        }
        if (lane == 0) {
            float y0 = label[(size_t)node * NCLS + 0];
            float y1 = label[(size_t)node * NCLS + 1];
            lsum = softplusf(-(y0 * ps)) + softplusf(-(y1 * ps));
            float l0 = p0 + bb[0], l1 = p1 + bb[1];
            int pred = (l1 > l0) ? 1 : 0;
            int truth = (y1 > y0) ? 1 : 0;
            csum = (pred == truth) ? 1.f : 0.f;
        }
    }
    if (lane == 0) { sl[wid] = lsum; sc2[wid] = csum; }
    __syncthreads();
    if (threadIdx.x == 0) {
        blockpart[blockIdx.x * 2 + 0] = sl[0] + sl[1] + sl[2] + sl[3];
        blockpart[blockIdx.x * 2 + 1] = sc2[0] + sc2[1] + sc2[2] + sc2[3];
    }
}

__global__ __launch_bounds__(256) void k_final(const float* __restrict__ bp,
                                               float* __restrict__ out, int nb) {
    __shared__ float sl[256], sc2[256];
    int t = threadIdx.x;
    float l = 0.f, c = 0.f;
    for (int i = t; i < nb; i += 256) { l += bp[i * 2]; c += bp[i * 2 + 1]; }
    sl[t] = l; sc2[t] = c;
    __syncthreads();
    for (int o = 128; o > 0; o >>= 1) {
        if (t < o) { sl[t] += sl[t + o]; sc2[t] += sc2[t + o]; }
        __syncthreads();
    }
    if (t == 0) { out[0] = sl[0]; out[1] = sc2[0] * (1.0f / NMASK); }
}

// ---------------- launch ----------------
extern "C" void kernel_launch(void* const* d_in, const int* in_sizes, int n_in,
                              void* d_out, int out_size, void* d_ws, size_t ws_size,
                              hipStream_t stream) {
    const float* x      = (const float*)d_in[0];
    const float* label  = (const float*)d_in[1];
    const int*   idx    = (const int*)d_in[2];
    const int*   src    = (const int*)d_in[3];
    const int*   dst    = (const int*)d_in[4];
    const float* vals   = (const float*)d_in[5];
    const float* h0     = (const float*)d_in[6];
    const float* Ws     = (const float*)d_in[7];
    const float* Vs     = (const float*)d_in[8];
    const float* alphas = (const float*)d_in[9];
    const float* Wc     = (const float*)d_in[10];
    const float* bb     = (const float*)d_in[11];
    const float* u      = (const float*)d_in[12];
    float* out = (float*)d_out;

    // fully un-aliased layout (~92 MB; ws is ~268 MB per harness fill size)
    char* p = (char*)d_ws;
    __hip_bfloat16* aggcb = (__hip_bfloat16*)p; p += (size_t)N_NODES * DOUT * 2;  // 12.8 MB
    __hip_bfloat16* xb    = (__hip_bfloat16*)p; p += (size_t)N_NODES * DIN * 2;   // 25.6 MB
    unsigned char*  h8    = (unsigned char*)p;  p += (size_t)N_NODES * DOUT;      // 6.4 MB
    __hip_bfloat16* hbf   = (__hip_bfloat16*)p; p += (size_t)N_NODES * DOUT * 2;  // 12.8 MB
    uint2*          edh   = (uint2*)p;          p += (size_t)TE * 8;              // 12 MB
    uint2*          ebkt  = (uint2*)p;          p += (size_t)TE * 8;              // 12 MB
    int*            offs  = (int*)p;            p += 200064 * 4;                  // ~0.8 MB
    int*            bh    = (int*)p;            p += (size_t)BHN * 4;             // 288 KB
    int*            sc    = (int*)p;            p += (size_t)BHN * 4;             // 288 KB
    int*            bsums = (int*)p;            p += 4096 * 4;
    __hip_bfloat16* WsT   = (__hip_bfloat16*)p; p += (size_t)NHOP * DOUT * DIN * 2;  // 128 KB
    __hip_bfloat16* VsT   = (__hip_bfloat16*)p; p += (size_t)NHOP * DOUT * DOUT * 2; // 64 KB
    float*          blockpart = (float*)p;      p += LOSS_BLOCKS * 2 * 4;         // 20 KB

    // bucket-binned CSR build; prep (h0->fp8, x->bf16, W/V transpose) hidden under bbin
    k_bhist<<<NBLKA, 256, 0, stream>>>(dst, bh);
    k_scanA<<<SCANBLKS, SCT, 0, stream>>>(bh, sc, bsums, BHN);
    k_scanB<<<1, SCT, 0, stream>>>(bsums, SCANBLKS);
    k_scanC<<<SCANBLKS, SCT, 0, stream>>>(sc, bsums, BHN);
    k_bbin_prep<<<NBLKA + PREPBLK, 256, 0, stream>>>(src, dst, vals, sc, ebkt,
                                                     h0, h8, x, xb, Ws, Vs, WsT, VsT);
    k_bsort<<<NBUCK, 512, 0, stream>>>(ebkt, sc, edh, offs);

    const int MMBLK = (N_NODES + 63) / 64;  // 782
    // hop 1: gather h0(fp8) -> agg; h1 = sigmoid(x@W0 + agg@V0) -> fp8 only
    k_agg<<<(N_NODES + 3) / 4, 256, 0, stream>>>(h8, edh, offs, alphas, aggcb);
    k_mm<<<MMBLK, 256, 0, stream>>>(xb, WsT, aggcb, VsT, h8, nullptr, N_NODES, DIN, DOUT);
    // hop 2: gather h1(fp8) -> agg; h2 = sigmoid(x@W1 + agg@V1) -> bf16 (for loss)
    k_agg<<<(N_NODES + 3) / 4, 256, 0, stream>>>(h8, edh, offs, alphas + NDEV, aggcb);
    k_mm<<<MMBLK, 256, 0, stream>>>(xb, WsT + (size_t)DOUT * DIN, aggcb,
                                    VsT + (size_t)DOUT * DOUT, nullptr, hbf,
                                    N_NODES, DIN, DOUT);

    k_loss<<<LOSS_BLOCKS, 256, 0, stream>>>(hbf, label, idx, u, Wc, bb, blockpart, NMASK);
    k_final<<<1, 256, 0, stream>>>(blockpart, out, LOSS_BLOCKS);
}

// Round 17
// 170.902 us; speedup vs baseline: 15.4162x; 1.0207x over previous
//
#include <hip/hip_runtime.h>
#include <hip/hip_bf16.h>

#define N_NODES 50000
#define DIN     256
#define DOUT    128
#define NCLS    2
#define NHOP    2
#define NDEV    3
#define EDG     500000
#define TE      (NDEV*EDG)
#define NMASK   10000
#define LOSS_BLOCKS 2500             // one masked node per wave

#define BUCK    256
#define NBUCK   196                  // ceil(50000/256)
#define CH      4096                 // edges per binning block
#define NBLKA   367                  // ceil(TE/CH)
#define BHN     (NBUCK*NBLKA)        // 71,932
#define SCT     512
#define SCANBLKS ((BHN + SCT - 1) / SCT)   // 141

typedef __attribute__((ext_vector_type(8))) short bf16x8;   // 8 bf16 = 4 VGPRs
typedef __attribute__((ext_vector_type(4))) float f32x4;
typedef __attribute__((ext_vector_type(2))) float f32x2;

__device__ __forceinline__ float softplusf(float a) {
    return fmaxf(a, 0.f) + log1pf(expf(-fabsf(a)));
}

// fp8 e4m3 (OCP on gfx950) helpers via HW pack/unpack
__device__ __forceinline__ f32x2 fp8lo(unsigned g) {
    return __builtin_amdgcn_cvt_pk_f32_fp8(g, false);
}
__device__ __forceinline__ f32x2 fp8hi(unsigned g) {
    return __builtin_amdgcn_cvt_pk_f32_fp8(g, true);
}
__device__ __forceinline__ unsigned char fp8enc1(float v) {
    return (unsigned char)(__builtin_amdgcn_cvt_pk_fp8_f32(v, v, 0, false) & 0xFF);
}

// ---------------- bucket-binned CSR build (write-amp ~1x) ----------------

__global__ __launch_bounds__(256) void k_bhist(const int* __restrict__ dst,
                                               int* __restrict__ bh) {
    __shared__ int hist[NBUCK];
    int blk = blockIdx.x, tid = threadIdx.x;
    for (int i = tid; i < NBUCK; i += 256) hist[i] = 0;
    __syncthreads();
    int base = blk * CH;
    int lim = min(base + CH, TE);
    for (int i = base + tid; i < lim; i += 256) atomicAdd(&hist[dst[i] >> 8], 1);
    __syncthreads();
    for (int i = tid; i < NBUCK; i += 256) bh[(size_t)i * NBLKA + blk] = hist[i];
}

__global__ __launch_bounds__(SCT) void k_scanA(const int* __restrict__ in,
                                               int* __restrict__ out,
                                               int* __restrict__ bsums, int n) {
    __shared__ int s[SCT];
    int tid = threadIdx.x, gid = blockIdx.x * SCT + tid;
    int v = (gid < n) ? in[gid] : 0;
    s[tid] = v; __syncthreads();
    for (int o = 1; o < SCT; o <<= 1) {
        int t = (tid >= o) ? s[tid - o] : 0;
        __syncthreads();
        s[tid] += t;
        __syncthreads();
    }
    if (gid < n) out[gid] = s[tid] - v;          // exclusive
    if (tid == SCT - 1) bsums[blockIdx.x] = s[SCT - 1];
}

// single-block carry-looped exclusive scan (handles nb > SCT)
__global__ __launch_bounds__(SCT) void k_scanB(int* __restrict__ bsums, int nb) {
    __shared__ int s[SCT];
    int tid = threadIdx.x;
    int carry = 0;
    for (int base = 0; base < nb; base += SCT) {
        int v = (base + tid < nb) ? bsums[base + tid] : 0;
        s[tid] = v; __syncthreads();
        for (int o = 1; o < SCT; o <<= 1) {
            int t = (tid >= o) ? s[tid - o] : 0;
            __syncthreads();
            s[tid] += t;
            __syncthreads();
        }
        if (base + tid < nb) bsums[base + tid] = s[tid] - v + carry;
        carry += s[SCT - 1];
        __syncthreads();
    }
}

__global__ __launch_bounds__(SCT) void k_scanC(int* __restrict__ out,
                                               const int* __restrict__ bsums, int n) {
    int gid = blockIdx.x * SCT + threadIdx.x;
    if (gid < n) out[gid] += bsums[blockIdx.x];
}

// merged: bin edges into bucket-grouped array (blocks < NBLKA) | prep conversions
// (blocks >= NBLKA). x is consumed fp32 directly by k_mm (no bf16 copy).
#define PREP_A (N_NODES * DOUT / 4)          // float4 units of h0
#define PREP_W (NHOP * (DIN * DOUT + DOUT * DOUT))
#define PREPBLK ((PREP_A + PREP_W + 255) / 256)
__global__ __launch_bounds__(256) void k_bbin_prep(const int* __restrict__ src,
                                                   const int* __restrict__ dst,
                                                   const float* __restrict__ vals,
                                                   const int* __restrict__ sc,
                                                   uint2* __restrict__ ebkt,
                                                   const float* __restrict__ h0,
                                                   unsigned char* __restrict__ h8,
                                                   const float* __restrict__ Ws,
                                                   const float* __restrict__ Vs,
                                                   __hip_bfloat16* __restrict__ WsT,
                                                   __hip_bfloat16* __restrict__ VsT) {
    __shared__ int cur[NBUCK];
    int blk = blockIdx.x, tid = threadIdx.x;
    if (blk < NBLKA) {
        // ---- binning: runs of ~21 edges (168B) per bucket per block ----
        for (int i = tid; i < NBUCK; i += 256) cur[i] = sc[(size_t)i * NBLKA + blk];
        __syncthreads();
        int base = blk * CH;
        int lim = min(base + CH, TE);
        for (int i = base + tid; i < lim; i += 256) {
            int d = i / EDG;
            int n = dst[i];
            int bu = n >> 8;
            int pos = atomicAdd(&cur[bu], 1);
            ebkt[pos] = make_uint2((unsigned)src[i] | ((unsigned)d << 16) |
                                   ((unsigned)(n & 255) << 18),
                                   __float_as_uint(vals[i]));
        }
    } else {
        // ---- prep: h0 -> fp8, W/V transpose+bf16 ----
        int i = (blk - NBLKA) * 256 + tid;
        if (i < PREP_A) {
            float4 f = ((const float4*)h0)[i];
            int r = 0;
            r = __builtin_amdgcn_cvt_pk_fp8_f32(f.x, f.y, r, false);
            r = __builtin_amdgcn_cvt_pk_fp8_f32(f.z, f.w, r, true);
            ((unsigned*)h8)[i] = (unsigned)r;
        } else {
            int j = i - PREP_A;
            if (j < NHOP * DIN * DOUT) {
                int hop = j / (DIN * DOUT);
                int r = j % (DIN * DOUT);
                int k = r >> 7, n = r & 127;
                WsT[(size_t)hop * DOUT * DIN + (size_t)n * DIN + k] = __float2bfloat16(Ws[j]);
            } else if (j < PREP_W) {
                int j2 = j - NHOP * DIN * DOUT;
                int hop = j2 / (DOUT * DOUT);
                int r = j2 % (DOUT * DOUT);
                int k = r >> 7, n = r & 127;
                VsT[(size_t)hop * DOUT * DOUT + (size_t)n * DOUT + k] = __float2bfloat16(Vs[j2]);
            }
        }
    }
}

// per-bucket counting sort by node (512 threads/block);
// emits {src|dev<<16, val} edge array + per-node offsets
__global__ __launch_bounds__(512) void k_bsort(const uint2* __restrict__ ebkt,
                                               const int* __restrict__ sc,
                                               uint2* __restrict__ edh,
                                               int* __restrict__ offs) {
    __shared__ int cnt[BUCK], start[BUCK + 1], cur[BUCK];
    int b = blockIdx.x, tid = threadIdx.x;
    int beg = sc[(size_t)b * NBLKA];
    int end = (b + 1 < NBUCK) ? sc[(size_t)(b + 1) * NBLKA] : TE;
    if (tid < BUCK) { cnt[tid] = 0; cur[tid] = 0; }
    __syncthreads();
    for (int e = beg + tid; e < end; e += 512)
        atomicAdd(&cnt[(ebkt[e].x >> 18) & 255], 1);
    __syncthreads();
    if (tid == 0) {
        int acc = 0;
        for (int i = 0; i < BUCK; ++i) { start[i] = acc; acc += cnt[i]; }
        start[BUCK] = acc;
    }
    __syncthreads();
    if (tid < BUCK) {
        int n = b * BUCK + tid;
        if (n < N_NODES) offs[n] = beg + start[tid];
    }
    if (b == 0 && tid == 511) offs[N_NODES] = TE;
    for (int e = beg + tid; e < end; e += 512) {
        uint2 v = ebkt[e];
        int dl = (v.x >> 18) & 255;
        int pos = beg + start[dl] + atomicAdd(&cur[dl], 1);
        edh[pos] = make_uint2(v.x & 0x3FFFFu, v.y);   // src | dev<<16, val
    }
}

// ---------------- sparse aggregation: one wave per node, 8 edges/iter --------------
// lane = grp(0..7)*8 + cw(0..7). Software-pipelined: next batch's edh meta is loaded
// one iteration ahead, so the gather (which depends on meta) issues at iter start.
__global__ __launch_bounds__(256) void k_agg(const unsigned char* __restrict__ h8,
                                             const uint2* __restrict__ edh,
                                             const int* __restrict__ offs,
                                             const float* __restrict__ alpha_hop,
                                             __hip_bfloat16* __restrict__ aggcb) {
    int wid = threadIdx.x >> 6;
    int lane = threadIdx.x & 63;
    int n = blockIdx.x * 4 + wid;
    if (n >= N_NODES) return;
    float a0 = alpha_hop[0], a1 = alpha_hop[1], a2 = alpha_hop[2];
    int grp = lane >> 3;         // edge slot within the 8-edge batch
    int cw = lane & 7;           // 16-byte chunk of the 128B fp8 row
    int beg = offs[n], end = offs[n + 1];
    float a[16];
#pragma unroll
    for (int j = 0; j < 16; ++j) a[j] = 0.f;

    int e = beg;
    uint2 q = make_uint2(0u, 0u);
    if (e < end) {
        int rem = end - e;
        q = edh[e + (grp < rem ? grp : 0)];
    }
    while (e < end) {
        int enext = e + 8;
        uint2 qn = q;
        if (enext < end) {
            int remn = end - enext;
            qn = edh[enext + (grp < remn ? grp : 0)];   // prefetch next batch meta
        }
        int rem = end - e;
        int d = (q.x >> 16) & 3;
        float wt = __uint_as_float(q.y) * (d == 0 ? a0 : (d == 1 ? a1 : a2));
        wt = (grp < rem) ? wt : 0.f;
        uint4 g = *(const uint4*)(h8 + (size_t)(q.x & 0xFFFFu) * DOUT + cw * 16);
#pragma unroll
        for (int wv = 0; wv < 4; ++wv) {
            unsigned gw = (&g.x)[wv];
            f32x2 lo = fp8lo(gw), hi = fp8hi(gw);
            a[wv * 4 + 0] += wt * lo[0];
            a[wv * 4 + 1] += wt * lo[1];
            a[wv * 4 + 2] += wt * hi[0];
            a[wv * 4 + 3] += wt * hi[1];
        }
        q = qn;
        e = enext;
    }
    // fold the 8 edge-groups (lane bits 3,4,5)
#pragma unroll
    for (int j = 0; j < 16; ++j) {
        a[j] += __shfl_xor(a[j], 8, 64);
        a[j] += __shfl_xor(a[j], 16, 64);
        a[j] += __shfl_xor(a[j], 32, 64);
    }
    if (grp == 0) {               // lanes 0..7 write cols cw*16 .. cw*16+15
        union { __hip_bfloat16 h[8]; uint4 u; } pk0, pk1;
#pragma unroll
        for (int j = 0; j < 8; ++j) {
            pk0.h[j] = __float2bfloat16(a[j]);
            pk1.h[j] = __float2bfloat16(a[8 + j]);
        }
        *(uint4*)(aggcb + (size_t)n * DOUT + cw * 16) = pk0.u;
        *(uint4*)(aggcb + (size_t)n * DOUT + cw * 16 + 8) = pk1.u;
    }
}

// ---------------- fused MFMA GEMM: h = sigmoid(A1@B1 + A2@B2) ----------------------
// A1 is fp32 (x), converted to bf16 during LDS staging; A2/BTs are bf16.
// BM=64 tile (782 blocks -> ~3 blocks/CU), 4 waves (2x2), wave = 32x64 via
// 2x4 mfma_f32_16x16x32_bf16 frags. LDS-staged A and B (verified-better vs direct).
__global__ __launch_bounds__(256) void k_mm(const float* __restrict__ A1f,
                                            const __hip_bfloat16* __restrict__ BT1,
                                            const __hip_bfloat16* __restrict__ A2,
                                            const __hip_bfloat16* __restrict__ BT2,
                                            unsigned char* __restrict__ C8,
                                            __hip_bfloat16* __restrict__ Cbf,
                                            int M, int K1, int K2) {
    __shared__ short As[64][40];    // stride 40: bank-starts spread, <=2-way (free)
    __shared__ short Bs[128][40];
    int tid = threadIdx.x;
    int lane = tid & 63;
    int w = tid >> 6;
    int wr = (w >> 1) * 32, wc = (w & 1) * 64;
    int lr = lane & 15, kg = lane >> 4;
    int row0 = blockIdx.x * 64;

    f32x4 acc[2][4];
#pragma unroll
    for (int mi = 0; mi < 2; ++mi)
#pragma unroll
        for (int ni = 0; ni < 4; ++ni) acc[mi][ni] = (f32x4){0.f, 0.f, 0.f, 0.f};

#pragma unroll
    for (int seg = 0; seg < 2; ++seg) {
        const __hip_bfloat16* BT = seg ? BT2 : BT1;
        int K = seg ? K2 : K1;
        for (int k0 = 0; k0 < K; k0 += 32) {
            {   // stage A tile: 64 rows x 32 k, 8 elems per thread
                int r = tid >> 2, kc = (tid & 3) * 8;
                int gr = row0 + r;
                bf16x8 g = {};
                if (seg == 0) {
                    if (gr < M) {   // fp32 -> bf16 convert in staging
                        const float4* ap = (const float4*)(A1f + (size_t)gr * K + k0 + kc);
                        float4 f0 = ap[0], f1 = ap[1];
                        union { __hip_bfloat16 h[8]; bf16x8 v; } pk;
                        pk.h[0] = __float2bfloat16(f0.x);
                        pk.h[1] = __float2bfloat16(f0.y);
                        pk.h[2] = __float2bfloat16(f0.z);
                        pk.h[3] = __float2bfloat16(f0.w);
                        pk.h[4] = __float2bfloat16(f1.x);
                        pk.h[5] = __float2bfloat16(f1.y);
                        pk.h[6] = __float2bfloat16(f1.z);
                        pk.h[7] = __float2bfloat16(f1.w);
                        g = pk.v;
                    }
                } else {
                    if (gr < M) g = *(const bf16x8*)(A2 + (size_t)gr * K + k0 + kc);
                }
                *(bf16x8*)&As[r][kc] = g;
            }
#pragma unroll
            for (int j = 0; j < 2; ++j) {           // stage BT tile: 512 chunks
                int c = tid + j * 256;
                int r = c >> 2, kc = (c & 3) * 8;
                *(bf16x8*)&Bs[r][kc] = *(const bf16x8*)(BT + (size_t)r * K + k0 + kc);
            }
            __syncthreads();
            bf16x8 af[2], bfr[4];
#pragma unroll
            for (int i = 0; i < 2; ++i)
                af[i] = *(const bf16x8*)&As[wr + i * 16 + lr][kg * 8];
#pragma unroll
            for (int i = 0; i < 4; ++i)
                bfr[i] = *(const bf16x8*)&Bs[wc + i * 16 + lr][kg * 8];
#pragma unroll
            for (int mi = 0; mi < 2; ++mi)
#pragma unroll
                for (int ni = 0; ni < 4; ++ni)
                    acc[mi][ni] = __builtin_amdgcn_mfma_f32_16x16x32_bf16(
                        af[mi], bfr[ni], acc[mi][ni], 0, 0, 0);
            __syncthreads();
        }
    }

#pragma unroll
    for (int mi = 0; mi < 2; ++mi) {
#pragma unroll
        for (int r = 0; r < 4; ++r) {
            int row = row0 + wr + mi * 16 + kg * 4 + r;   // C/D: row=(lane>>4)*4+reg
            if (row < M) {
#pragma unroll
                for (int ni = 0; ni < 4; ++ni) {
                    int col = wc + ni * 16 + lr;          // C/D: col=lane&15
                    float v = acc[mi][ni][r];
                    v = 1.f / (1.f + __expf(-v));
                    if (C8)  C8[(size_t)row * DOUT + col] = fp8enc1(v);
                    if (Cbf) Cbf[(size_t)row * DOUT + col] = __float2bfloat16(v);
                }
            }
        }
    }
}

// ---------------- masked loss + accuracy: one node per wave ----------------
__global__ __launch_bounds__(256) void k_loss(const __hip_bfloat16* __restrict__ h,
                                              const float* __restrict__ label,
                                              const int* __restrict__ idx,
                                              const float* __restrict__ u,
                                              const float* __restrict__ Wc,
                                              const float* __restrict__ bb,
                                              float* __restrict__ blockpart, int Mtot) {
    __shared__ float sl[4], sc2[4];
    int wid = threadIdx.x >> 6;
    int lane = threadIdx.x & 63;
    int w = blockIdx.x * 4 + wid;
    float lsum = 0.f, csum = 0.f;
    if (w < Mtot) {
        int node = idx[w];
        float v0 = __bfloat162float(h[(size_t)node * DOUT + lane]);
        float v1 = __bfloat162float(h[(size_t)node * DOUT + 64 + lane]);
        float ps = v0 * u[lane] + v1 * u[64 + lane];
        float p0 = v0 * Wc[lane * 2 + 0] + v1 * Wc[(lane + 64) * 2 + 0];
        float p1 = v0 * Wc[lane * 2 + 1] + v1 * Wc[(lane + 64) * 2 + 1];
#pragma unroll
        for (int o = 32; o > 0; o >>= 1) {
            ps += __shfl_xor(ps, o, 64);
            p0 += __shfl_xor(p0, o, 64);
            p1 += __shfl_xor(p1, o, 64);
        }
        if (lane == 0) {
            float y0 = label[(size_t)node * NCLS + 0];
            float y1 = label[(size_t)node * NCLS + 1];
            lsum = softplusf(-(y0 * ps)) + softplusf(-(y1 * ps));
            float l0 = p0 + bb[0], l1 = p1 + bb[1];
            int pred = (l1 > l0) ? 1 : 0;
            int truth = (y1 > y0) ? 1 : 0;
            csum = (pred == truth) ? 1.f : 0.f;
        }
    }
    if (lane == 0) { sl[wid] = lsum; sc2[wid] = csum; }
    __syncthreads();
    if (threadIdx.x == 0) {
        blockpart[blockIdx.x * 2 + 0] = sl[0] + sl[1] + sl[2] + sl[3];
        blockpart[blockIdx.x * 2 + 1] = sc2[0] + sc2[1] + sc2[2] + sc2[3];
    }
}

__global__ __launch_bounds__(256) void k_final(const float* __restrict__ bp,
                                               float* __restrict__ out, int nb) {
    __shared__ float sl[256], sc2[256];
    int t = threadIdx.x;
    float l = 0.f, c = 0.f;
    for (int i = t; i < nb; i += 256) { l += bp[i * 2]; c += bp[i * 2 + 1]; }
    sl[t] = l; sc2[t] = c;
    __syncthreads();
    for (int o = 128; o > 0; o >>= 1) {
        if (t < o) { sl[t] += sl[t + o]; sc2[t] += sc2[t + o]; }
        __syncthreads();
    }
    if (t == 0) { out[0] = sl[0]; out[1] = sc2[0] * (1.0f / NMASK); }
}

// ---------------- launch ----------------
extern "C" void kernel_launch(void* const* d_in, const int* in_sizes, int n_in,
                              void* d_out, int out_size, void* d_ws, size_t ws_size,
                              hipStream_t stream) {
    const float* x      = (const float*)d_in[0];
    const float* label  = (const float*)d_in[1];
    const int*   idx    = (const int*)d_in[2];
    const int*   src    = (const int*)d_in[3];
    const int*   dst    = (const int*)d_in[4];
    const float* vals   = (const float*)d_in[5];
    const float* h0     = (const float*)d_in[6];
    const float* Ws     = (const float*)d_in[7];
    const float* Vs     = (const float*)d_in[8];
    const float* alphas = (const float*)d_in[9];
    const float* Wc     = (const float*)d_in[10];
    const float* bb     = (const float*)d_in[11];
    const float* u      = (const float*)d_in[12];
    float* out = (float*)d_out;

    // fully un-aliased layout (~70 MB; ws is ~268 MB per harness fill size)
    char* p = (char*)d_ws;
    __hip_bfloat16* aggcb = (__hip_bfloat16*)p; p += (size_t)N_NODES * DOUT * 2;  // 12.8 MB
    unsigned char*  h8    = (unsigned char*)p;  p += (size_t)N_NODES * DOUT;      // 6.4 MB
    __hip_bfloat16* hbf   = (__hip_bfloat16*)p; p += (size_t)N_NODES * DOUT * 2;  // 12.8 MB
    uint2*          edh   = (uint2*)p;          p += (size_t)TE * 8;              // 12 MB
    uint2*          ebkt  = (uint2*)p;          p += (size_t)TE * 8;              // 12 MB
    int*            offs  = (int*)p;            p += 200064 * 4;                  // ~0.8 MB
    int*            bh    = (int*)p;            p += (size_t)BHN * 4;             // 288 KB
    int*            sc    = (int*)p;            p += (size_t)BHN * 4;             // 288 KB
    int*            bsums = (int*)p;            p += 4096 * 4;
    __hip_bfloat16* WsT   = (__hip_bfloat16*)p; p += (size_t)NHOP * DOUT * DIN * 2;  // 128 KB
    __hip_bfloat16* VsT   = (__hip_bfloat16*)p; p += (size_t)NHOP * DOUT * DOUT * 2; // 64 KB
    float*          blockpart = (float*)p;      p += LOSS_BLOCKS * 2 * 4;         // 20 KB

    // bucket-binned CSR build; prep (h0->fp8, W/V transpose) hidden under bbin
    k_bhist<<<NBLKA, 256, 0, stream>>>(dst, bh);
    k_scanA<<<SCANBLKS, SCT, 0, stream>>>(bh, sc, bsums, BHN);
    k_scanB<<<1, SCT, 0, stream>>>(bsums, SCANBLKS);
    k_scanC<<<SCANBLKS, SCT, 0, stream>>>(sc, bsums, BHN);
    k_bbin_prep<<<NBLKA + PREPBLK, 256, 0, stream>>>(src, dst, vals, sc, ebkt,
                                                     h0, h8, Ws, Vs, WsT, VsT);
    k_bsort<<<NBUCK, 512, 0, stream>>>(ebkt, sc, edh, offs);

    const int MMBLK = (N_NODES + 63) / 64;  // 782
    // hop 1: gather h0(fp8) -> agg; h1 = sigmoid(x@W0 + agg@V0) -> fp8 only
    k_agg<<<(N_NODES + 3) / 4, 256, 0, stream>>>(h8, edh, offs, alphas, aggcb);
    k_mm<<<MMBLK, 256, 0, stream>>>(x, WsT, aggcb, VsT, h8, nullptr, N_NODES, DIN, DOUT);
    // hop 2: gather h1(fp8) -> agg; h2 = sigmoid(x@W1 + agg@V1) -> bf16 (for loss)
    k_agg<<<(N_NODES + 3) / 4, 256, 0, stream>>>(h8, edh, offs, alphas + NDEV, aggcb);
    k_mm<<<MMBLK, 256, 0, stream>>>(x, WsT + (size_t)DOUT * DIN, aggcb,
                                    VsT + (size_t)DOUT * DOUT, nullptr, hbf,
                                    N_NODES, DIN, DOUT);

    k_loss<<<LOSS_BLOCKS, 256, 0, stream>>>(hbf, label, idx, u, Wc, bb, blockpart, NMASK);
    k_final<<<1, 256, 0, stream>>>(blockpart, out, LOSS_BLOCKS);
}